// Round 10
// baseline (1309.110 us; speedup 1.0000x reference)
//
#include <hip/hip_runtime.h>

#define OFFX 0.0f
#define OFFY -40.0f
#define OFFZ -3.0f
#define BNEPS 1e-3f
#define NCH 128   // bn partial chunks
#define NG 9      // conv tap groups (3 taps each)

// ---------------- keys ----------------
__global__ void keys_k(const int* __restrict__ coords, int n, int D, int H, int W,
                       int* __restrict__ keys) {
  int i = blockIdx.x * 256 + threadIdx.x;
  if (i < n) {
    const int* c = coords + (size_t)i * 4;
    keys[i] = ((c[0] * D + c[1]) * H + c[2]) * W + c[3];
  }
}

// ---------------- neighbor tables (subm: scale=1, stride: scale=2) ----------------
__global__ void nbr_k(const int* __restrict__ coords, int np, const int* __restrict__ keys, int nk,
                      int D, int H, int W, int scale, int* __restrict__ nbr) {
  int t = blockIdx.x * 256 + threadIdx.x;
  if (t >= np * 27) return;
  int p = t / 27, k = t % 27;
  int kz = k / 9 - 1, ky = (k / 3) % 3 - 1, kx = k % 3 - 1;
  const int* c = coords + (size_t)p * 4;
  int z = c[1] * scale + kz, y = c[2] * scale + ky, x = c[3] * scale + kx;
  int r = -1;
  if (z >= 0 && z < D && y >= 0 && y < H && x >= 0 && x < W) {
    int q = ((c[0] * D + z) * H + y) * W + x;
    int lo = 0, hi = nk;
    while (lo < hi) { int m = (lo + hi) >> 1; if (keys[m] < q) lo = m + 1; else hi = m; }
    if (lo < nk && keys[lo] == q) r = lo;
  }
  nbr[t] = r;
}

// ---------------- sparse 3x3x3 conv: LDS tile-GEMM (TP=64), fused BN+ReLU,
// software-pipelined gather: tap k+1's loads issue before tap k's FMA phase ----------------
template<int CIN, int COUT, bool BN>
__global__ __launch_bounds__(256) void convg_k(const float* __restrict__ feats,
                                               const int* __restrict__ nbr,
                                               const float* __restrict__ w, int n,
                                               float* __restrict__ partial, int gstride,
                                               const float* __restrict__ scsh) {
  constexpr int TP = 64;
  constexpr int LDP = 68;        // row stride: conflict-free both phases
  constexpr int CO = COUT / 16;  // cols per thread
  constexpr int NITEMS = TP * CIN / 4;
  constexpr int NIT = (NITEMS + 255) / 256;
  __shared__ float G[CIN * LDP];
  int tid = threadIdx.x;
  int pg = tid >> 4, cg = tid & 15;
  int p0 = blockIdx.x * TP;
  int k0 = blockIdx.y * 3;

  // preload the 3 taps' neighbor indices for this thread's staging slots
  int sidx[NIT][3];
#pragma unroll
  for (int it = 0; it < NIT; it++) {
    int ch = tid + it * 256;
    int r = ch & 63;
    int p = p0 + r;
    bool ok = (ch < NITEMS) && (p < n);
    const int* nb = nbr + (size_t)p * 27 + k0;
#pragma unroll
    for (int kk = 0; kk < 3; kk++) sidx[it][kk] = ok ? nb[kk] : -1;
  }
  // prefetch tap 0 features into registers (unconditional load, clamp idx to 0)
  float4 pf[NIT];
#pragma unroll
  for (int it = 0; it < NIT; it++) {
    int ch = tid + it * 256;
    int c4 = ch >> 6;
    int idx = sidx[it][0]; if (idx < 0) idx = 0;
    if (ch < NITEMS) pf[it] = *(const float4*)(feats + (size_t)idx * CIN + c4 * 4);
  }

  float acc[4][CO];
#pragma unroll
  for (int i = 0; i < 4; i++)
#pragma unroll
    for (int j = 0; j < CO; j++) acc[i][j] = 0.f;

  for (int kk = 0; kk < 3; kk++) {
    __syncthreads();  // prior compute done reading LDS
    // store registers -> LDS (BN+ReLU applied; absent neighbor -> 0)
#pragma unroll
    for (int it = 0; it < NIT; it++) {
      int ch = tid + it * 256;
      if (ch < NITEMS) {
        int r = ch & 63, c4 = ch >> 6;
        float4 fv = pf[it];
        if constexpr (BN) {
          const float4 s4 = *(const float4*)(scsh + c4 * 4);
          const float4 h4 = *(const float4*)(scsh + CIN + c4 * 4);
          fv.x = fmaxf(fmaf(fv.x, s4.x, h4.x), 0.f);
          fv.y = fmaxf(fmaf(fv.y, s4.y, h4.y), 0.f);
          fv.z = fmaxf(fmaf(fv.z, s4.z, h4.z), 0.f);
          fv.w = fmaxf(fmaf(fv.w, s4.w, h4.w), 0.f);
        }
        if (sidx[it][kk] < 0) fv = make_float4(0.f, 0.f, 0.f, 0.f);
        G[(c4 * 4 + 0) * LDP + r] = fv.x;
        G[(c4 * 4 + 1) * LDP + r] = fv.y;
        G[(c4 * 4 + 2) * LDP + r] = fv.z;
        G[(c4 * 4 + 3) * LDP + r] = fv.w;
      }
    }
    // issue next tap's gather now; vmcnt wait lands at next iteration's store
    if (kk < 2) {
#pragma unroll
      for (int it = 0; it < NIT; it++) {
        int ch = tid + it * 256;
        int c4 = ch >> 6;
        int idx = sidx[it][kk + 1]; if (idx < 0) idx = 0;
        if (ch < NITEMS) pf[it] = *(const float4*)(feats + (size_t)idx * CIN + c4 * 4);
      }
    }
    __syncthreads();
    const float* wk = w + (size_t)k0 * CIN * COUT + (size_t)kk * CIN * COUT + cg * CO;
#pragma unroll 8
    for (int c = 0; c < CIN; c++) {
      float4 g4 = *(const float4*)&G[c * LDP + pg * 4];
      float wv[CO];
      if constexpr (CO == 4)      *(float4*)wv = *(const float4*)(wk + c * COUT);
      else if constexpr (CO == 2) *(float2*)wv = *(const float2*)(wk + c * COUT);
      else                        wv[0] = wk[c * COUT];
      float gp[4] = {g4.x, g4.y, g4.z, g4.w};
#pragma unroll
      for (int i = 0; i < 4; i++)
#pragma unroll
        for (int j = 0; j < CO; j++) acc[i][j] = fmaf(gp[i], wv[j], acc[i][j]);
    }
  }
#pragma unroll
  for (int i = 0; i < 4; i++) {
    int p = p0 + pg * 4 + i;
    if (p < n) {
      float* dst = partial + (size_t)blockIdx.y * gstride + (size_t)p * COUT + cg * CO;
      if constexpr (CO == 4)      *(float4*)dst = *(float4*)acc[i];
      else if constexpr (CO == 2) *(float2*)dst = *(float2*)acc[i];
      else                        dst[0] = acc[i][0];
    }
  }
}

// ---------------- bn: sum partials -> pre + stats; last block finalizes (sc, sh) ----------------
__global__ void bn_k(const float* __restrict__ partial, int G, int gstride, int n, int C,
                     float* __restrict__ pre, float* __restrict__ stats,
                     const float* __restrict__ bnp, float* __restrict__ scsh,
                     int* __restrict__ ctr) {
  __shared__ float l1[256], l2[256];
  __shared__ int lastf;
  int t = threadIdx.x;
  int total = n * C;
  float s1 = 0.f, s2 = 0.f;
  for (int i = blockIdx.x * 256 + t; i < total; i += NCH * 256) {
    float v = 0.f;
    for (int g = 0; g < G; g++) v += partial[(size_t)g * gstride + i];
    pre[i] = v;
    s1 += v; s2 += v * v;
  }
  l1[t] = s1; l2[t] = s2;
  for (int s = 128; s >= C; s >>= 1) {
    __syncthreads();
    if (t < s) { l1[t] += l1[t + s]; l2[t] += l2[t + s]; }
  }
  __syncthreads();
  if (t < C) {
    stats[((size_t)blockIdx.x * C + t) * 2] = l1[t];
    stats[((size_t)blockIdx.x * C + t) * 2 + 1] = l2[t];
  }
  __threadfence();
  __syncthreads();
  if (t == 0) lastf = (atomicAdd(ctr, 1) == NCH - 1) ? 1 : 0;
  __syncthreads();
  if (lastf) {
    __threadfence();
    if (t < C) {
      float a1 = 0.f, a2 = 0.f;
      for (int ch = 0; ch < NCH; ch++) {
        a1 += stats[((size_t)ch * C + t) * 2];
        a2 += stats[((size_t)ch * C + t) * 2 + 1];
      }
      float m = a1 / n;
      float v = a2 / n - m * m;
      float sc = bnp[t] / sqrtf(v + BNEPS);
      scsh[t] = sc;
      scsh[C + t] = bnp[C + t] - m * sc;
    }
  }
}

// ---------------- points_mean ----------------
__global__ void pm_k(const float* __restrict__ vf, const int* __restrict__ c0, int n0,
                     float* __restrict__ pm, float* __restrict__ out1) {
  int i = blockIdx.x * 256 + threadIdx.x;
  if (i >= n0) return;
  float b = (float)c0[(size_t)i * 4];
  float x = vf[(size_t)i * 4], y = vf[(size_t)i * 4 + 1], z = vf[(size_t)i * 4 + 2];
  pm[(size_t)i * 4] = b; pm[(size_t)i * 4 + 1] = x; pm[(size_t)i * 4 + 2] = y; pm[(size_t)i * 4 + 3] = z;
  out1[(size_t)i * 4] = b; out1[(size_t)i * 4 + 1] = x; out1[(size_t)i * 4 + 2] = y; out1[(size_t)i * 4 + 3] = z;
}

// ---------------- knn prep ----------------
__global__ void knnprep_k(const int* __restrict__ coords, int nl, float vx, float vy, float vz,
                          float4* __restrict__ kp4, int* __restrict__ bs) {
  int i = blockIdx.x * 256 + threadIdx.x;
  if (i >= nl) return;
  const int* c = coords + (size_t)i * 4;
  kp4[i] = make_float4(OFFX + (c[3] + 0.5f) * vx,
                       OFFY + (c[2] + 0.5f) * vy,
                       OFFZ + (c[1] + 0.5f) * vz, (float)c[0]);
  if (c[0] == 0 && (i + 1 == nl || coords[(size_t)(i + 1) * 4] == 1)) bs[0] = i + 1;
}

// ---------------- 3-NN: one WAVE per unknown; med3-based sorted insert; shfl merge ----------------
__global__ __launch_bounds__(256) void knn_k(const float4* __restrict__ pm4, int n0,
                                             const float4* __restrict__ kp4, int nl,
                                             const int* __restrict__ bsp,
                                             float* __restrict__ wv, int* __restrict__ iv) {
  int wave = threadIdx.x >> 6, lane = threadIdx.x & 63;
  int u = blockIdx.x * 4 + wave;
  if (u >= n0) return;  // wave-uniform
  float4 up = pm4[u];
  int bs = bsp[0];
  int lo = (up.x == 0.f) ? 0 : bs;
  int hi = (up.x == 0.f) ? bs : nl;
  float ux = up.y, uy = up.z, uz = up.w;
  float d0 = 3e38f, d1 = 3e38f, d2 = 3e38f;
  int i0 = -1, i1 = -1, i2 = -1;
  // sorted-triple insert: distances via min/med3 (3 ops), indices via cmp+cndmask
#define INS1(DD, GI) { \
    bool l0 = (DD) < d0, l1 = (DD) < d1, l2 = (DD) < d2; \
    i2 = l2 ? (l1 ? i1 : (GI)) : i2; \
    i1 = l1 ? (l0 ? i0 : (GI)) : i1; \
    i0 = l0 ? (GI) : i0; \
    float t1_ = __builtin_amdgcn_fmed3f(d0, d1, (DD)); \
    float t2_ = __builtin_amdgcn_fmed3f(d1, d2, (DD)); \
    d0 = fminf(d0, (DD)); d1 = t1_; d2 = t2_; }
  for (int e = lo + lane; e < hi; e += 64) {
    float4 q = kp4[e];
    float dx = ux - q.x, dy = uy - q.y, dz = uz - q.z;
    float dd = fmaf(dx, dx, fmaf(dy, dy, dz * dz));
    INS1(dd, e)
  }
  // butterfly merge of 64 local top-3 triples
#pragma unroll
  for (int off = 1; off < 64; off <<= 1) {
    float e0 = __shfl_xor(d0, off), e1 = __shfl_xor(d1, off), e2 = __shfl_xor(d2, off);
    int j0 = __shfl_xor(i0, off), j1 = __shfl_xor(i1, off), j2 = __shfl_xor(i2, off);
    INS1(e0, j0) INS1(e1, j1) INS1(e2, j2)
  }
#undef INS1
  if (lane == 0) {
    float w0 = 1.f / (d0 + 1e-8f), w1 = 1.f / (d1 + 1e-8f), w2 = 1.f / (d2 + 1e-8f);
    float s = w0 + w1 + w2;
    wv[(size_t)u * 3] = w0 / s; wv[(size_t)u * 3 + 1] = w1 / s; wv[(size_t)u * 3 + 2] = w2 / s;
    iv[(size_t)u * 3] = i0; iv[(size_t)u * 3 + 1] = i1; iv[(size_t)u * 3 + 2] = i2;
  }
}

// interp with fused BN+ReLU on source features (f = PRE, scsh of source layer)
__global__ void interp_k(const float* __restrict__ f, int C, const float* __restrict__ scsh,
                         const float* __restrict__ wv, const int* __restrict__ iv, int n0,
                         float* __restrict__ X, int xoff) {
  int t = blockIdx.x * 256 + threadIdx.x;
  if (t >= n0 * C) return;
  int u = t / C, c = t % C;
  float sc = scsh[c], sh = scsh[C + c];
  float a0 = fmaxf(fmaf(f[(size_t)iv[(size_t)u * 3]     * C + c], sc, sh), 0.f);
  float a1 = fmaxf(fmaf(f[(size_t)iv[(size_t)u * 3 + 1] * C + c], sc, sh), 0.f);
  float a2 = fmaxf(fmaf(f[(size_t)iv[(size_t)u * 3 + 2] * C + c], sc, sh), 0.f);
  X[(size_t)u * 160 + xoff + c] = wv[(size_t)u * 3] * a0 + wv[(size_t)u * 3 + 1] * a1
                                + wv[(size_t)u * 3 + 2] * a2;
}

// ---------------- extra 1x1 conv with fused input BN ----------------
__global__ __launch_bounds__(256) void conv1x1_k(const float* __restrict__ f,
                                                 const float* __restrict__ scsh,
                                                 const float* __restrict__ we, int n,
                                                 float* __restrict__ out) {
  __shared__ float rows[256];
  int t = threadIdx.x;
  int p = blockIdx.x * 4 + (t >> 6), c = t & 63;
  rows[t] = (p < n) ? fmaxf(fmaf(f[(size_t)p * 64 + c], scsh[c], scsh[64 + c]), 0.f) : 0.f;
  __syncthreads();
  if (p >= n) return;
  const float* fr = rows + (t >> 6) * 64;
  float a = 0.f;
#pragma unroll 16
  for (int ci = 0; ci < 64; ci++) a = fmaf(fr[ci], we[ci * 64 + c], a);
  out[(size_t)p * 64 + c] = a;
}

// ---------------- dense scatter with fused BN+ReLU ----------------
__global__ void scatter_k(const float* __restrict__ pre, const float* __restrict__ scsh,
                          const int* __restrict__ c3, int n3, float* __restrict__ out0) {
  int t = blockIdx.x * 256 + threadIdx.x;
  if (t >= n3 * 64) return;
  int p = t >> 6, c = t & 63;
  const int* cc = c3 + (size_t)p * 4;
  size_t o = ((((size_t)cc[0] * 64 + c) * 6 + cc[1]) * 100 + cc[2]) * 100 + cc[3];
  out0[o] = fmaxf(fmaf(pre[t], scsh[c], scsh[64 + c]), 0.f);
}

// ---------------- head ----------------
__global__ __launch_bounds__(256) void head_k(const float* __restrict__ X,
                                              const float* __restrict__ fcw,
                                              const float* __restrict__ clsw,
                                              const float* __restrict__ regw,
                                              int n0, float* __restrict__ outc,
                                              float* __restrict__ outr) {
  __shared__ float fl[64 * 161];
  int t = threadIdx.x;
  for (int i = t; i < 64 * 160; i += 256) {
    int r = i / 160, c = i % 160;
    fl[r * 161 + c] = fcw[i];
  }
  __syncthreads();
  int wave = t >> 6, lane = t & 63;
  int u = blockIdx.x * 4 + wave;
  if (u >= n0) return;
  const float* xr = X + (size_t)u * 160;
  const float* wr = fl + (size_t)lane * 161;
  float a = 0.f;
#pragma unroll 8
  for (int i = 0; i < 160; i++) a = fmaf(xr[i], wr[i], a);
  float c = a * clsw[lane];
  float r0 = a * regw[lane], r1 = a * regw[64 + lane], r2 = a * regw[128 + lane];
  for (int off = 32; off; off >>= 1) {
    c  += __shfl_down(c, off);
    r0 += __shfl_down(r0, off);
    r1 += __shfl_down(r1, off);
    r2 += __shfl_down(r2, off);
  }
  if (lane == 0) {
    outc[u] = c;
    outr[(size_t)u * 3] = r0; outr[(size_t)u * 3 + 1] = r1; outr[(size_t)u * 3 + 2] = r2;
  }
}

// ---------------- host ----------------
extern "C" void kernel_launch(void* const* d_in, const int* in_sizes, int n_in,
                              void* d_out, int out_size, void* d_ws, size_t ws_size,
                              hipStream_t stream) {
  const float* vf  = (const float*)d_in[0];
  const int* c0 = (const int*)d_in[1];
  const int* c1 = (const int*)d_in[2];
  const int* c2 = (const int*)d_in[3];
  const int* c3 = (const int*)d_in[4];
  const float* w00 = (const float*)d_in[5];  const float* b00 = (const float*)d_in[6];
  const float* w01 = (const float*)d_in[7];  const float* b01 = (const float*)d_in[8];
  const float* wd0 = (const float*)d_in[9];  const float* bd0 = (const float*)d_in[10];
  const float* w10 = (const float*)d_in[11]; const float* b10 = (const float*)d_in[12];
  const float* w11 = (const float*)d_in[13]; const float* b11 = (const float*)d_in[14];
  const float* wd1 = (const float*)d_in[15]; const float* bd1 = (const float*)d_in[16];
  const float* w20 = (const float*)d_in[17]; const float* b20 = (const float*)d_in[18];
  const float* w21 = (const float*)d_in[19]; const float* b21 = (const float*)d_in[20];
  const float* w22 = (const float*)d_in[21]; const float* b22 = (const float*)d_in[22];
  const float* wd2 = (const float*)d_in[23]; const float* bd2 = (const float*)d_in[24];
  const float* w30 = (const float*)d_in[25]; const float* b30 = (const float*)d_in[26];
  const float* w31 = (const float*)d_in[27]; const float* b31 = (const float*)d_in[28];
  const float* w32 = (const float*)d_in[29]; const float* b32 = (const float*)d_in[30];
  const float* we  = (const float*)d_in[31]; const float* be  = (const float*)d_in[32];
  const float* fcw = (const float*)d_in[33];
  const float* clsw = (const float*)d_in[34];
  const float* regw = (const float*)d_in[35];

  int N0 = in_sizes[1] / 4, N1 = in_sizes[2] / 4, N2 = in_sizes[3] / 4, N3 = in_sizes[4] / 4;
  int maxN = N0; if (N1 > maxN) maxN = N1; if (N2 > maxN) maxN = N2; if (N3 > maxN) maxN = N3;

  auto cdiv = [](int a, int b) { return (a + b - 1) / b; };
  char* p = (char*)d_ws;
  auto alloc = [&](size_t bytes) { char* r = p; p += (bytes + 255) & ~(size_t)255; return r; };

  int* keys0 = (int*)alloc((size_t)N0 * 4);
  int* keys1 = (int*)alloc((size_t)N1 * 4);
  int* keys2 = (int*)alloc((size_t)N2 * 4);
  int* keys3 = (int*)alloc((size_t)N3 * 4);
  int* nbr0  = (int*)alloc((size_t)N0 * 27 * 4);
  int* nbrs1 = (int*)alloc((size_t)N1 * 27 * 4);
  int* nbr1  = (int*)alloc((size_t)N1 * 27 * 4);
  int* nbrs2 = (int*)alloc((size_t)N2 * 27 * 4);
  int* nbr2  = (int*)alloc((size_t)N2 * 27 * 4);
  int* nbrs3 = (int*)alloc((size_t)N3 * 27 * 4);
  int* nbr3  = (int*)alloc((size_t)N3 * 27 * 4);
  float* FA = (float*)alloc((size_t)maxN * 64 * 4);
  float* FB = (float*)alloc((size_t)maxN * 64 * 4);
  float* FC = (float*)alloc((size_t)maxN * 64 * 4);
  float* stats = (float*)alloc((size_t)NCH * 64 * 2 * 4);
  float* SC = (float*)alloc((size_t)15 * 128 * 4);   // per-layer (sc, sh)
  int* ctrs = (int*)alloc(16 * 4);
  float* wv = (float*)alloc((size_t)N0 * 3 * 4);
  int*   iv = (int*)alloc((size_t)N0 * 3 * 4);
  float* X  = (float*)alloc((size_t)N0 * 160 * 4);
  float* pmb = (float*)alloc((size_t)N0 * 4 * 4);
  float4* kp1 = (float4*)alloc((size_t)N1 * 16);
  float4* kp2 = (float4*)alloc((size_t)N2 * 16);
  float4* kp3 = (float4*)alloc((size_t)N3 * 16);
  int* bsA = (int*)alloc(32);

  float* out0 = (float*)d_out;
  float* out1 = out0 + 7680000;        // points_mean
  float* outc = out1 + (size_t)N0 * 4; // cls
  float* outr = outc + N0;             // reg
  float* partial = out0;               // conv partial scratch until final memset

  auto scsh = [&](int L) { return SC + (size_t)L * 128; };

  hipMemsetAsync(ctrs, 0, 16 * 4, stream);
  keys_k<<<cdiv(N0, 256), 256, 0, stream>>>(c0, N0, 41, 800, 800, keys0);
  keys_k<<<cdiv(N1, 256), 256, 0, stream>>>(c1, N1, 21, 400, 400, keys1);
  keys_k<<<cdiv(N2, 256), 256, 0, stream>>>(c2, N2, 11, 200, 200, keys2);
  keys_k<<<cdiv(N3, 256), 256, 0, stream>>>(c3, N3, 6, 100, 100, keys3);
  nbr_k<<<cdiv(N0 * 27, 256), 256, 0, stream>>>(c0, N0, keys0, N0, 41, 800, 800, 1, nbr0);
  nbr_k<<<cdiv(N1 * 27, 256), 256, 0, stream>>>(c1, N1, keys0, N0, 41, 800, 800, 2, nbrs1);
  nbr_k<<<cdiv(N1 * 27, 256), 256, 0, stream>>>(c1, N1, keys1, N1, 21, 400, 400, 1, nbr1);
  nbr_k<<<cdiv(N2 * 27, 256), 256, 0, stream>>>(c2, N2, keys1, N1, 21, 400, 400, 2, nbrs2);
  nbr_k<<<cdiv(N2 * 27, 256), 256, 0, stream>>>(c2, N2, keys2, N2, 11, 200, 200, 1, nbr2);
  nbr_k<<<cdiv(N3 * 27, 256), 256, 0, stream>>>(c3, N3, keys2, N2, 11, 200, 200, 2, nbrs3);
  nbr_k<<<cdiv(N3 * 27, 256), 256, 0, stream>>>(c3, N3, keys3, N3, 6, 100, 100, 1, nbr3);
  pm_k<<<cdiv(N0, 256), 256, 0, stream>>>(vf, c0, N0, pmb, out1);
  knnprep_k<<<cdiv(N1, 256), 256, 0, stream>>>(c1, N1, 0.2f, 0.2f, 0.4f, kp1, bsA + 0);
  knnprep_k<<<cdiv(N2, 256), 256, 0, stream>>>(c2, N2, 0.4f, 0.4f, 0.8f, kp2, bsA + 1);
  knnprep_k<<<cdiv(N3, 256), 256, 0, stream>>>(c3, N3, 0.8f, 0.8f, 1.6f, kp3, bsA + 2);

  auto conv = [&](const float* fin, const int* nb, const float* wptr, int n, int cin, int cout,
                  const float* ss) {
    dim3 g(cdiv(n, 64), NG);
    int gs = n * cout;
    if (cin == 4 && cout == 16)
      convg_k<4, 16, false><<<g, 256, 0, stream>>>(fin, nb, wptr, n, partial, gs, nullptr);
    else if (cin == 16 && cout == 16)
      convg_k<16, 16, true><<<g, 256, 0, stream>>>(fin, nb, wptr, n, partial, gs, ss);
    else if (cin == 16 && cout == 32)
      convg_k<16, 32, true><<<g, 256, 0, stream>>>(fin, nb, wptr, n, partial, gs, ss);
    else if (cin == 32 && cout == 32)
      convg_k<32, 32, true><<<g, 256, 0, stream>>>(fin, nb, wptr, n, partial, gs, ss);
    else if (cin == 32 && cout == 64)
      convg_k<32, 64, true><<<g, 256, 0, stream>>>(fin, nb, wptr, n, partial, gs, ss);
    else
      convg_k<64, 64, true><<<g, 256, 0, stream>>>(fin, nb, wptr, n, partial, gs, ss);
  };
  auto bnp = [&](const float* bnpar, int n, int C, float* pre, int L) {
    bn_k<<<NCH, 256, 0, stream>>>(partial, NG, n * C, n, C, pre, stats, bnpar, scsh(L), ctrs + L);
  };
  auto knn = [&](const float4* kp4, const int* bsl, int nl, const float* f, int C, int L,
                 int xoff) {
    knn_k<<<cdiv(N0, 4), 256, 0, stream>>>((const float4*)pmb, N0, kp4, nl, bsl, wv, iv);
    interp_k<<<cdiv(N0 * C, 256), 256, 0, stream>>>(f, C, scsh(L), wv, iv, N0, X, xoff);
  };

  conv(vf, nbr0, w00, N0, 4, 16, nullptr);   bnp(b00, N0, 16, FA, 0);
  conv(FA, nbr0, w01, N0, 16, 16, scsh(0));  bnp(b01, N0, 16, FB, 1);
  conv(FB, nbrs1, wd0, N1, 16, 32, scsh(1)); bnp(bd0, N1, 32, FA, 2);
  conv(FA, nbr1, w10, N1, 32, 32, scsh(2));  bnp(b10, N1, 32, FB, 3);
  conv(FB, nbr1, w11, N1, 32, 32, scsh(3));  bnp(b11, N1, 32, FA, 4);
  knn(kp1, bsA + 0, N1, FA, 32, 4, 0);
  conv(FA, nbrs2, wd1, N2, 32, 64, scsh(4)); bnp(bd1, N2, 64, FB, 5);
  conv(FB, nbr2, w20, N2, 64, 64, scsh(5));  bnp(b20, N2, 64, FA, 6);
  conv(FA, nbr2, w21, N2, 64, 64, scsh(6));  bnp(b21, N2, 64, FB, 7);
  conv(FB, nbr2, w22, N2, 64, 64, scsh(7));  bnp(b22, N2, 64, FA, 8);
  knn(kp2, bsA + 1, N2, FA, 64, 8, 32);
  conv(FA, nbrs3, wd2, N3, 64, 64, scsh(8)); bnp(bd2, N3, 64, FB, 9);
  conv(FB, nbr3, w30, N3, 64, 64, scsh(9));  bnp(b30, N3, 64, FA, 10);
  conv(FA, nbr3, w31, N3, 64, 64, scsh(10)); bnp(b31, N3, 64, FB, 11);
  conv(FB, nbr3, w32, N3, 64, 64, scsh(11)); bnp(b32, N3, 64, FA, 12);
  knn(kp3, bsA + 2, N3, FA, 64, 12, 96);

  conv1x1_k<<<cdiv(N3, 4), 256, 0, stream>>>(FA, scsh(12), we, N3, FC);
  bn_k<<<NCH, 256, 0, stream>>>(FC, 1, 0, N3, 64, FB, stats, be, scsh(13), ctrs + 13);
  hipMemsetAsync(d_out, 0, (size_t)7680000 * 4, stream);
  scatter_k<<<cdiv(N3 * 64, 256), 256, 0, stream>>>(FB, scsh(13), c3, N3, out0);
  head_k<<<cdiv(N0, 4), 256, 0, stream>>>(X, fcw, clsw, regw, N0, outc, outr);
}

// Round 11
// 1189.510 us; speedup vs baseline: 1.1005x; 1.1005x over previous
//
#include <hip/hip_runtime.h>

#define OFFX 0.0f
#define OFFY -40.0f
#define OFFZ -3.0f
#define BNEPS 1e-3f
#define NCH 128   // bn partial chunks
#define NG 9      // conv tap groups (3 taps each)

// ---------------- keys ----------------
__global__ void keys_k(const int* __restrict__ coords, int n, int D, int H, int W,
                       int* __restrict__ keys) {
  int i = blockIdx.x * 256 + threadIdx.x;
  if (i < n) {
    const int* c = coords + (size_t)i * 4;
    keys[i] = ((c[0] * D + c[1]) * H + c[2]) * W + c[3];
  }
}

// ---------------- neighbor tables (subm: scale=1, stride: scale=2) ----------------
__global__ void nbr_k(const int* __restrict__ coords, int np, const int* __restrict__ keys, int nk,
                      int D, int H, int W, int scale, int* __restrict__ nbr) {
  int t = blockIdx.x * 256 + threadIdx.x;
  if (t >= np * 27) return;
  int p = t / 27, k = t % 27;
  int kz = k / 9 - 1, ky = (k / 3) % 3 - 1, kx = k % 3 - 1;
  const int* c = coords + (size_t)p * 4;
  int z = c[1] * scale + kz, y = c[2] * scale + ky, x = c[3] * scale + kx;
  int r = -1;
  if (z >= 0 && z < D && y >= 0 && y < H && x >= 0 && x < W) {
    int q = ((c[0] * D + z) * H + y) * W + x;
    int lo = 0, hi = nk;
    while (lo < hi) { int m = (lo + hi) >> 1; if (keys[m] < q) lo = m + 1; else hi = m; }
    if (lo < nk && keys[lo] == q) r = lo;
  }
  nbr[t] = r;
}

// ---------------- sparse 3x3x3 conv: LDS tile-GEMM, BLOCK=128 / TP=32 ----------------
// Same per-thread ratios as the TP=64/256-thread version (4 staged float4, CIN iters of
// b128-read + 4xCO FMA, 16 outputs) but 2x blocks and 2-wave barriers.
template<int CIN, int COUT, bool BN>
__global__ __launch_bounds__(128) void convg_k(const float* __restrict__ feats,
                                               const int* __restrict__ nbr,
                                               const float* __restrict__ w, int n,
                                               float* __restrict__ partial, int gstride,
                                               const float* __restrict__ scsh) {
  constexpr int TP = 32;
  constexpr int LDP = 36;        // 144B row stride: 16B-aligned, conflict-free both phases
  constexpr int CO = COUT / 16;  // cols per thread
  __shared__ float G[CIN * LDP];
  int tid = threadIdx.x;
  int pg = tid >> 4, cg = tid & 15;   // pg 0..7 (4 points each), cg 0..15 (CO cols each)
  int p0 = blockIdx.x * TP;
  int k0 = blockIdx.y * 3;
  float acc[4][CO];
#pragma unroll
  for (int i = 0; i < 4; i++)
#pragma unroll
    for (int j = 0; j < CO; j++) acc[i][j] = 0.f;

  for (int kk = 0; kk < 3; kk++) {
    int k = k0 + kk;
    __syncthreads();
    // staging: r spans tile within wave halves -> bank-free writes; fused BN+ReLU
    for (int ch = tid; ch < TP * CIN / 4; ch += 128) {
      int r = ch & (TP - 1), c4 = ch / TP;
      int p = p0 + r;
      int idx = (p < n) ? nbr[(size_t)p * 27 + k] : -1;
      float4 fv = make_float4(0.f, 0.f, 0.f, 0.f);
      if (idx >= 0) {
        fv = *(const float4*)(feats + (size_t)idx * CIN + c4 * 4);
        if constexpr (BN) {
          const float4 s4 = *(const float4*)(scsh + c4 * 4);
          const float4 h4 = *(const float4*)(scsh + CIN + c4 * 4);
          fv.x = fmaxf(fmaf(fv.x, s4.x, h4.x), 0.f);
          fv.y = fmaxf(fmaf(fv.y, s4.y, h4.y), 0.f);
          fv.z = fmaxf(fmaf(fv.z, s4.z, h4.z), 0.f);
          fv.w = fmaxf(fmaf(fv.w, s4.w, h4.w), 0.f);
        }
      }
      G[(c4 * 4 + 0) * LDP + r] = fv.x;
      G[(c4 * 4 + 1) * LDP + r] = fv.y;
      G[(c4 * 4 + 2) * LDP + r] = fv.z;
      G[(c4 * 4 + 3) * LDP + r] = fv.w;
    }
    __syncthreads();
    const float* wk = w + (size_t)k * CIN * COUT + cg * CO;
#pragma unroll 8
    for (int c = 0; c < CIN; c++) {
      float4 g4 = *(const float4*)&G[c * LDP + pg * 4];
      float wv[CO];
      if constexpr (CO == 4)      *(float4*)wv = *(const float4*)(wk + c * COUT);
      else if constexpr (CO == 2) *(float2*)wv = *(const float2*)(wk + c * COUT);
      else                        wv[0] = wk[c * COUT];
      float gp[4] = {g4.x, g4.y, g4.z, g4.w};
#pragma unroll
      for (int i = 0; i < 4; i++)
#pragma unroll
        for (int j = 0; j < CO; j++) acc[i][j] = fmaf(gp[i], wv[j], acc[i][j]);
    }
  }
#pragma unroll
  for (int i = 0; i < 4; i++) {
    int p = p0 + pg * 4 + i;
    if (p < n) {
      float* dst = partial + (size_t)blockIdx.y * gstride + (size_t)p * COUT + cg * CO;
      if constexpr (CO == 4)      *(float4*)dst = *(float4*)acc[i];
      else if constexpr (CO == 2) *(float2*)dst = *(float2*)acc[i];
      else                        dst[0] = acc[i][0];
    }
  }
}

// ---------------- bn: sum partials -> pre + stats; last block finalizes (sc, sh) ----------------
__global__ void bn_k(const float* __restrict__ partial, int G, int gstride, int n, int C,
                     float* __restrict__ pre, float* __restrict__ stats,
                     const float* __restrict__ bnp, float* __restrict__ scsh,
                     int* __restrict__ ctr) {
  __shared__ float l1[256], l2[256];
  __shared__ int lastf;
  int t = threadIdx.x;
  int total = n * C;
  float s1 = 0.f, s2 = 0.f;
  for (int i = blockIdx.x * 256 + t; i < total; i += NCH * 256) {
    float v = 0.f;
    for (int g = 0; g < G; g++) v += partial[(size_t)g * gstride + i];
    pre[i] = v;
    s1 += v; s2 += v * v;
  }
  l1[t] = s1; l2[t] = s2;
  for (int s = 128; s >= C; s >>= 1) {
    __syncthreads();
    if (t < s) { l1[t] += l1[t + s]; l2[t] += l2[t + s]; }
  }
  __syncthreads();
  if (t < C) {
    stats[((size_t)blockIdx.x * C + t) * 2] = l1[t];
    stats[((size_t)blockIdx.x * C + t) * 2 + 1] = l2[t];
  }
  __threadfence();
  __syncthreads();
  if (t == 0) lastf = (atomicAdd(ctr, 1) == NCH - 1) ? 1 : 0;
  __syncthreads();
  if (lastf) {
    __threadfence();
    if (t < C) {
      float a1 = 0.f, a2 = 0.f;
      for (int ch = 0; ch < NCH; ch++) {
        a1 += stats[((size_t)ch * C + t) * 2];
        a2 += stats[((size_t)ch * C + t) * 2 + 1];
      }
      float m = a1 / n;
      float v = a2 / n - m * m;
      float sc = bnp[t] / sqrtf(v + BNEPS);
      scsh[t] = sc;
      scsh[C + t] = bnp[C + t] - m * sc;
    }
  }
}

// ---------------- points_mean ----------------
__global__ void pm_k(const float* __restrict__ vf, const int* __restrict__ c0, int n0,
                     float* __restrict__ pm, float* __restrict__ out1) {
  int i = blockIdx.x * 256 + threadIdx.x;
  if (i >= n0) return;
  float b = (float)c0[(size_t)i * 4];
  float x = vf[(size_t)i * 4], y = vf[(size_t)i * 4 + 1], z = vf[(size_t)i * 4 + 2];
  pm[(size_t)i * 4] = b; pm[(size_t)i * 4 + 1] = x; pm[(size_t)i * 4 + 2] = y; pm[(size_t)i * 4 + 3] = z;
  out1[(size_t)i * 4] = b; out1[(size_t)i * 4 + 1] = x; out1[(size_t)i * 4 + 2] = y; out1[(size_t)i * 4 + 3] = z;
}

// ---------------- knn prep ----------------
__global__ void knnprep_k(const int* __restrict__ coords, int nl, float vx, float vy, float vz,
                          float4* __restrict__ kp4, int* __restrict__ bs) {
  int i = blockIdx.x * 256 + threadIdx.x;
  if (i >= nl) return;
  const int* c = coords + (size_t)i * 4;
  kp4[i] = make_float4(OFFX + (c[3] + 0.5f) * vx,
                       OFFY + (c[2] + 0.5f) * vy,
                       OFFZ + (c[1] + 0.5f) * vz, (float)c[0]);
  if (c[0] == 0 && (i + 1 == nl || coords[(size_t)(i + 1) * 4] == 1)) bs[0] = i + 1;
}

// ---------------- 3-NN: one WAVE per unknown; med3-based sorted insert; shfl merge ----------------
__global__ __launch_bounds__(256) void knn_k(const float4* __restrict__ pm4, int n0,
                                             const float4* __restrict__ kp4, int nl,
                                             const int* __restrict__ bsp,
                                             float* __restrict__ wv, int* __restrict__ iv) {
  int wave = threadIdx.x >> 6, lane = threadIdx.x & 63;
  int u = blockIdx.x * 4 + wave;
  if (u >= n0) return;  // wave-uniform
  float4 up = pm4[u];
  int bs = bsp[0];
  int lo = (up.x == 0.f) ? 0 : bs;
  int hi = (up.x == 0.f) ? bs : nl;
  float ux = up.y, uy = up.z, uz = up.w;
  float d0 = 3e38f, d1 = 3e38f, d2 = 3e38f;
  int i0 = -1, i1 = -1, i2 = -1;
#define INS1(DD, GI) { \
    bool l0 = (DD) < d0, l1 = (DD) < d1, l2 = (DD) < d2; \
    i2 = l2 ? (l1 ? i1 : (GI)) : i2; \
    i1 = l1 ? (l0 ? i0 : (GI)) : i1; \
    i0 = l0 ? (GI) : i0; \
    float t1_ = __builtin_amdgcn_fmed3f(d0, d1, (DD)); \
    float t2_ = __builtin_amdgcn_fmed3f(d1, d2, (DD)); \
    d0 = fminf(d0, (DD)); d1 = t1_; d2 = t2_; }
  for (int e = lo + lane; e < hi; e += 64) {
    float4 q = kp4[e];
    float dx = ux - q.x, dy = uy - q.y, dz = uz - q.z;
    float dd = fmaf(dx, dx, fmaf(dy, dy, dz * dz));
    INS1(dd, e)
  }
#pragma unroll
  for (int off = 1; off < 64; off <<= 1) {
    float e0 = __shfl_xor(d0, off), e1 = __shfl_xor(d1, off), e2 = __shfl_xor(d2, off);
    int j0 = __shfl_xor(i0, off), j1 = __shfl_xor(i1, off), j2 = __shfl_xor(i2, off);
    INS1(e0, j0) INS1(e1, j1) INS1(e2, j2)
  }
#undef INS1
  if (lane == 0) {
    float w0 = 1.f / (d0 + 1e-8f), w1 = 1.f / (d1 + 1e-8f), w2 = 1.f / (d2 + 1e-8f);
    float s = w0 + w1 + w2;
    wv[(size_t)u * 3] = w0 / s; wv[(size_t)u * 3 + 1] = w1 / s; wv[(size_t)u * 3 + 2] = w2 / s;
    iv[(size_t)u * 3] = i0; iv[(size_t)u * 3 + 1] = i1; iv[(size_t)u * 3 + 2] = i2;
  }
}

// interp with fused BN+ReLU on source features (f = PRE, scsh of source layer)
__global__ void interp_k(const float* __restrict__ f, int C, const float* __restrict__ scsh,
                         const float* __restrict__ wv, const int* __restrict__ iv, int n0,
                         float* __restrict__ X, int xoff) {
  int t = blockIdx.x * 256 + threadIdx.x;
  if (t >= n0 * C) return;
  int u = t / C, c = t % C;
  float sc = scsh[c], sh = scsh[C + c];
  float a0 = fmaxf(fmaf(f[(size_t)iv[(size_t)u * 3]     * C + c], sc, sh), 0.f);
  float a1 = fmaxf(fmaf(f[(size_t)iv[(size_t)u * 3 + 1] * C + c], sc, sh), 0.f);
  float a2 = fmaxf(fmaf(f[(size_t)iv[(size_t)u * 3 + 2] * C + c], sc, sh), 0.f);
  X[(size_t)u * 160 + xoff + c] = wv[(size_t)u * 3] * a0 + wv[(size_t)u * 3 + 1] * a1
                                + wv[(size_t)u * 3 + 2] * a2;
}

// ---------------- extra 1x1 conv with fused input BN ----------------
__global__ __launch_bounds__(256) void conv1x1_k(const float* __restrict__ f,
                                                 const float* __restrict__ scsh,
                                                 const float* __restrict__ we, int n,
                                                 float* __restrict__ out) {
  __shared__ float rows[256];
  int t = threadIdx.x;
  int p = blockIdx.x * 4 + (t >> 6), c = t & 63;
  rows[t] = (p < n) ? fmaxf(fmaf(f[(size_t)p * 64 + c], scsh[c], scsh[64 + c]), 0.f) : 0.f;
  __syncthreads();
  if (p >= n) return;
  const float* fr = rows + (t >> 6) * 64;
  float a = 0.f;
#pragma unroll 16
  for (int ci = 0; ci < 64; ci++) a = fmaf(fr[ci], we[ci * 64 + c], a);
  out[(size_t)p * 64 + c] = a;
}

// ---------------- dense scatter with fused BN+ReLU ----------------
__global__ void scatter_k(const float* __restrict__ pre, const float* __restrict__ scsh,
                          const int* __restrict__ c3, int n3, float* __restrict__ out0) {
  int t = blockIdx.x * 256 + threadIdx.x;
  if (t >= n3 * 64) return;
  int p = t >> 6, c = t & 63;
  const int* cc = c3 + (size_t)p * 4;
  size_t o = ((((size_t)cc[0] * 64 + c) * 6 + cc[1]) * 100 + cc[2]) * 100 + cc[3];
  out0[o] = fmaxf(fmaf(pre[t], scsh[c], scsh[64 + c]), 0.f);
}

// ---------------- head ----------------
__global__ __launch_bounds__(256) void head_k(const float* __restrict__ X,
                                              const float* __restrict__ fcw,
                                              const float* __restrict__ clsw,
                                              const float* __restrict__ regw,
                                              int n0, float* __restrict__ outc,
                                              float* __restrict__ outr) {
  __shared__ float fl[64 * 161];
  int t = threadIdx.x;
  for (int i = t; i < 64 * 160; i += 256) {
    int r = i / 160, c = i % 160;
    fl[r * 161 + c] = fcw[i];
  }
  __syncthreads();
  int wave = t >> 6, lane = t & 63;
  int u = blockIdx.x * 4 + wave;
  if (u >= n0) return;
  const float* xr = X + (size_t)u * 160;
  const float* wr = fl + (size_t)lane * 161;
  float a = 0.f;
#pragma unroll 8
  for (int i = 0; i < 160; i++) a = fmaf(xr[i], wr[i], a);
  float c = a * clsw[lane];
  float r0 = a * regw[lane], r1 = a * regw[64 + lane], r2 = a * regw[128 + lane];
  for (int off = 32; off; off >>= 1) {
    c  += __shfl_down(c, off);
    r0 += __shfl_down(r0, off);
    r1 += __shfl_down(r1, off);
    r2 += __shfl_down(r2, off);
  }
  if (lane == 0) {
    outc[u] = c;
    outr[(size_t)u * 3] = r0; outr[(size_t)u * 3 + 1] = r1; outr[(size_t)u * 3 + 2] = r2;
  }
}

// ---------------- host ----------------
extern "C" void kernel_launch(void* const* d_in, const int* in_sizes, int n_in,
                              void* d_out, int out_size, void* d_ws, size_t ws_size,
                              hipStream_t stream) {
  const float* vf  = (const float*)d_in[0];
  const int* c0 = (const int*)d_in[1];
  const int* c1 = (const int*)d_in[2];
  const int* c2 = (const int*)d_in[3];
  const int* c3 = (const int*)d_in[4];
  const float* w00 = (const float*)d_in[5];  const float* b00 = (const float*)d_in[6];
  const float* w01 = (const float*)d_in[7];  const float* b01 = (const float*)d_in[8];
  const float* wd0 = (const float*)d_in[9];  const float* bd0 = (const float*)d_in[10];
  const float* w10 = (const float*)d_in[11]; const float* b10 = (const float*)d_in[12];
  const float* w11 = (const float*)d_in[13]; const float* b11 = (const float*)d_in[14];
  const float* wd1 = (const float*)d_in[15]; const float* bd1 = (const float*)d_in[16];
  const float* w20 = (const float*)d_in[17]; const float* b20 = (const float*)d_in[18];
  const float* w21 = (const float*)d_in[19]; const float* b21 = (const float*)d_in[20];
  const float* w22 = (const float*)d_in[21]; const float* b22 = (const float*)d_in[22];
  const float* wd2 = (const float*)d_in[23]; const float* bd2 = (const float*)d_in[24];
  const float* w30 = (const float*)d_in[25]; const float* b30 = (const float*)d_in[26];
  const float* w31 = (const float*)d_in[27]; const float* b31 = (const float*)d_in[28];
  const float* w32 = (const float*)d_in[29]; const float* b32 = (const float*)d_in[30];
  const float* we  = (const float*)d_in[31]; const float* be  = (const float*)d_in[32];
  const float* fcw = (const float*)d_in[33];
  const float* clsw = (const float*)d_in[34];
  const float* regw = (const float*)d_in[35];

  int N0 = in_sizes[1] / 4, N1 = in_sizes[2] / 4, N2 = in_sizes[3] / 4, N3 = in_sizes[4] / 4;
  int maxN = N0; if (N1 > maxN) maxN = N1; if (N2 > maxN) maxN = N2; if (N3 > maxN) maxN = N3;

  auto cdiv = [](int a, int b) { return (a + b - 1) / b; };
  char* p = (char*)d_ws;
  auto alloc = [&](size_t bytes) { char* r = p; p += (bytes + 255) & ~(size_t)255; return r; };

  int* keys0 = (int*)alloc((size_t)N0 * 4);
  int* keys1 = (int*)alloc((size_t)N1 * 4);
  int* keys2 = (int*)alloc((size_t)N2 * 4);
  int* keys3 = (int*)alloc((size_t)N3 * 4);
  int* nbr0  = (int*)alloc((size_t)N0 * 27 * 4);
  int* nbrs1 = (int*)alloc((size_t)N1 * 27 * 4);
  int* nbr1  = (int*)alloc((size_t)N1 * 27 * 4);
  int* nbrs2 = (int*)alloc((size_t)N2 * 27 * 4);
  int* nbr2  = (int*)alloc((size_t)N2 * 27 * 4);
  int* nbrs3 = (int*)alloc((size_t)N3 * 27 * 4);
  int* nbr3  = (int*)alloc((size_t)N3 * 27 * 4);
  float* FA = (float*)alloc((size_t)maxN * 64 * 4);
  float* FB = (float*)alloc((size_t)maxN * 64 * 4);
  float* FC = (float*)alloc((size_t)maxN * 64 * 4);
  float* stats = (float*)alloc((size_t)NCH * 64 * 2 * 4);
  float* SC = (float*)alloc((size_t)15 * 128 * 4);   // per-layer (sc, sh)
  int* ctrs = (int*)alloc(16 * 4);
  float* wv = (float*)alloc((size_t)N0 * 3 * 4);
  int*   iv = (int*)alloc((size_t)N0 * 3 * 4);
  float* X  = (float*)alloc((size_t)N0 * 160 * 4);
  float* pmb = (float*)alloc((size_t)N0 * 4 * 4);
  float4* kp1 = (float4*)alloc((size_t)N1 * 16);
  float4* kp2 = (float4*)alloc((size_t)N2 * 16);
  float4* kp3 = (float4*)alloc((size_t)N3 * 16);
  int* bsA = (int*)alloc(32);

  float* out0 = (float*)d_out;
  float* out1 = out0 + 7680000;        // points_mean
  float* outc = out1 + (size_t)N0 * 4; // cls
  float* outr = outc + N0;             // reg
  float* partial = out0;               // conv partial scratch until final memset

  auto scsh = [&](int L) { return SC + (size_t)L * 128; };

  hipMemsetAsync(ctrs, 0, 16 * 4, stream);
  keys_k<<<cdiv(N0, 256), 256, 0, stream>>>(c0, N0, 41, 800, 800, keys0);
  keys_k<<<cdiv(N1, 256), 256, 0, stream>>>(c1, N1, 21, 400, 400, keys1);
  keys_k<<<cdiv(N2, 256), 256, 0, stream>>>(c2, N2, 11, 200, 200, keys2);
  keys_k<<<cdiv(N3, 256), 256, 0, stream>>>(c3, N3, 6, 100, 100, keys3);
  nbr_k<<<cdiv(N0 * 27, 256), 256, 0, stream>>>(c0, N0, keys0, N0, 41, 800, 800, 1, nbr0);
  nbr_k<<<cdiv(N1 * 27, 256), 256, 0, stream>>>(c1, N1, keys0, N0, 41, 800, 800, 2, nbrs1);
  nbr_k<<<cdiv(N1 * 27, 256), 256, 0, stream>>>(c1, N1, keys1, N1, 21, 400, 400, 1, nbr1);
  nbr_k<<<cdiv(N2 * 27, 256), 256, 0, stream>>>(c2, N2, keys1, N1, 21, 400, 400, 2, nbrs2);
  nbr_k<<<cdiv(N2 * 27, 256), 256, 0, stream>>>(c2, N2, keys2, N2, 11, 200, 200, 1, nbr2);
  nbr_k<<<cdiv(N3 * 27, 256), 256, 0, stream>>>(c3, N3, keys2, N2, 11, 200, 200, 2, nbrs3);
  nbr_k<<<cdiv(N3 * 27, 256), 256, 0, stream>>>(c3, N3, keys3, N3, 6, 100, 100, 1, nbr3);
  pm_k<<<cdiv(N0, 256), 256, 0, stream>>>(vf, c0, N0, pmb, out1);
  knnprep_k<<<cdiv(N1, 256), 256, 0, stream>>>(c1, N1, 0.2f, 0.2f, 0.4f, kp1, bsA + 0);
  knnprep_k<<<cdiv(N2, 256), 256, 0, stream>>>(c2, N2, 0.4f, 0.4f, 0.8f, kp2, bsA + 1);
  knnprep_k<<<cdiv(N3, 256), 256, 0, stream>>>(c3, N3, 0.8f, 0.8f, 1.6f, kp3, bsA + 2);

  auto conv = [&](const float* fin, const int* nb, const float* wptr, int n, int cin, int cout,
                  const float* ss) {
    dim3 g(cdiv(n, 32), NG);
    int gs = n * cout;
    if (cin == 4 && cout == 16)
      convg_k<4, 16, false><<<g, 128, 0, stream>>>(fin, nb, wptr, n, partial, gs, nullptr);
    else if (cin == 16 && cout == 16)
      convg_k<16, 16, true><<<g, 128, 0, stream>>>(fin, nb, wptr, n, partial, gs, ss);
    else if (cin == 16 && cout == 32)
      convg_k<16, 32, true><<<g, 128, 0, stream>>>(fin, nb, wptr, n, partial, gs, ss);
    else if (cin == 32 && cout == 32)
      convg_k<32, 32, true><<<g, 128, 0, stream>>>(fin, nb, wptr, n, partial, gs, ss);
    else if (cin == 32 && cout == 64)
      convg_k<32, 64, true><<<g, 128, 0, stream>>>(fin, nb, wptr, n, partial, gs, ss);
    else
      convg_k<64, 64, true><<<g, 128, 0, stream>>>(fin, nb, wptr, n, partial, gs, ss);
  };
  auto bnp = [&](const float* bnpar, int n, int C, float* pre, int L) {
    bn_k<<<NCH, 256, 0, stream>>>(partial, NG, n * C, n, C, pre, stats, bnpar, scsh(L), ctrs + L);
  };
  auto knn = [&](const float4* kp4, const int* bsl, int nl, const float* f, int C, int L,
                 int xoff) {
    knn_k<<<cdiv(N0, 4), 256, 0, stream>>>((const float4*)pmb, N0, kp4, nl, bsl, wv, iv);
    interp_k<<<cdiv(N0 * C, 256), 256, 0, stream>>>(f, C, scsh(L), wv, iv, N0, X, xoff);
  };

  conv(vf, nbr0, w00, N0, 4, 16, nullptr);   bnp(b00, N0, 16, FA, 0);
  conv(FA, nbr0, w01, N0, 16, 16, scsh(0));  bnp(b01, N0, 16, FB, 1);
  conv(FB, nbrs1, wd0, N1, 16, 32, scsh(1)); bnp(bd0, N1, 32, FA, 2);
  conv(FA, nbr1, w10, N1, 32, 32, scsh(2));  bnp(b10, N1, 32, FB, 3);
  conv(FB, nbr1, w11, N1, 32, 32, scsh(3));  bnp(b11, N1, 32, FA, 4);
  knn(kp1, bsA + 0, N1, FA, 32, 4, 0);
  conv(FA, nbrs2, wd1, N2, 32, 64, scsh(4)); bnp(bd1, N2, 64, FB, 5);
  conv(FB, nbr2, w20, N2, 64, 64, scsh(5));  bnp(b20, N2, 64, FA, 6);
  conv(FA, nbr2, w21, N2, 64, 64, scsh(6));  bnp(b21, N2, 64, FB, 7);
  conv(FB, nbr2, w22, N2, 64, 64, scsh(7));  bnp(b22, N2, 64, FA, 8);
  knn(kp2, bsA + 1, N2, FA, 64, 8, 32);
  conv(FA, nbrs3, wd2, N3, 64, 64, scsh(8)); bnp(bd2, N3, 64, FB, 9);
  conv(FB, nbr3, w30, N3, 64, 64, scsh(9));  bnp(b30, N3, 64, FA, 10);
  conv(FA, nbr3, w31, N3, 64, 64, scsh(10)); bnp(b31, N3, 64, FB, 11);
  conv(FB, nbr3, w32, N3, 64, 64, scsh(11)); bnp(b32, N3, 64, FA, 12);
  knn(kp3, bsA + 2, N3, FA, 64, 12, 96);

  conv1x1_k<<<cdiv(N3, 4), 256, 0, stream>>>(FA, scsh(12), we, N3, FC);
  bn_k<<<NCH, 256, 0, stream>>>(FC, 1, 0, N3, 64, FB, stats, be, scsh(13), ctrs + 13);
  hipMemsetAsync(d_out, 0, (size_t)7680000 * 4, stream);
  scatter_k<<<cdiv(N3 * 64, 256), 256, 0, stream>>>(FB, scsh(13), c3, N3, out0);
  head_k<<<cdiv(N0, 4), 256, 0, stream>>>(X, fcw, clsw, regw, N0, outc, outr);
}

// Round 13
// 961.734 us; speedup vs baseline: 1.3612x; 1.2368x over previous
//
#include <hip/hip_runtime.h>

#define OFFX 0.0f
#define OFFY -40.0f
#define OFFZ -3.0f
#define BNEPS 1e-3f
#define NCH 128   // bn partial chunks
#define NG 9      // conv tap groups (3 taps each)

typedef _Float16 h2_t __attribute__((ext_vector_type(2)));
__device__ inline h2_t u2h(unsigned u) { union { unsigned u; h2_t h; } x; x.u = u; return x.h; }
__device__ inline unsigned h2u(h2_t h) { union { unsigned u; h2_t h; } x; x.h = h; return x.u; }

// ---------------- keys ----------------
__global__ void keys_k(const int* __restrict__ coords, int n, int D, int H, int W,
                       int* __restrict__ keys) {
  int i = blockIdx.x * 256 + threadIdx.x;
  if (i < n) {
    const int* c = coords + (size_t)i * 4;
    keys[i] = ((c[0] * D + c[1]) * H + c[2]) * W + c[3];
  }
}

// ---------------- neighbor tables ----------------
__global__ void nbr_k(const int* __restrict__ coords, int np, const int* __restrict__ keys, int nk,
                      int D, int H, int W, int scale, int* __restrict__ nbr) {
  int t = blockIdx.x * 256 + threadIdx.x;
  if (t >= np * 27) return;
  int p = t / 27, k = t % 27;
  int kz = k / 9 - 1, ky = (k / 3) % 3 - 1, kx = k % 3 - 1;
  const int* c = coords + (size_t)p * 4;
  int z = c[1] * scale + kz, y = c[2] * scale + ky, x = c[3] * scale + kx;
  int r = -1;
  if (z >= 0 && z < D && y >= 0 && y < H && x >= 0 && x < W) {
    int q = ((c[0] * D + z) * H + y) * W + x;
    int lo = 0, hi = nk;
    while (lo < hi) { int m = (lo + hi) >> 1; if (keys[m] < q) lo = m + 1; else hi = m; }
    if (lo < nk && keys[lo] == q) r = lo;
  }
  nbr[t] = r;
}

// ---------------- weight prep: fp32 [27][CIN][COUT] -> h2 [27][CIN/2][COUT] ----------------
struct WPrep { const float* src; unsigned* dst; int cin; int cout; };
struct WP13 { WPrep l[13]; };
__global__ void wprep_k(WP13 a) {
  WPrep w = a.l[blockIdx.y];
  int cp2 = w.cin / 2;
  int tot = 27 * cp2 * w.cout;
  int i = blockIdx.x * 256 + threadIdx.x;
  if (i >= tot) return;
  int o = i % w.cout, rest = i / w.cout;
  int cp = rest % cp2, k = rest / cp2;
  float lo = w.src[((size_t)k * w.cin + 2 * cp) * w.cout + o];
  float hi = w.src[((size_t)k * w.cin + 2 * cp + 1) * w.cout + o];
  h2_t h; h[0] = (_Float16)lo; h[1] = (_Float16)hi;
  w.dst[i] = h2u(h);
}

// ---------------- layer-0 conv (fp32, CIN=4): LDS tile-GEMM TP=32 ----------------
template<int CIN, int COUT>
__global__ __launch_bounds__(128) void convg_k(const float* __restrict__ feats,
                                               const int* __restrict__ nbr,
                                               const float* __restrict__ w, int n,
                                               float* __restrict__ partial, int gstride) {
  constexpr int TP = 32;
  constexpr int LDP = 36;
  constexpr int CO = COUT / 16;
  __shared__ float G[CIN * LDP];
  int tid = threadIdx.x;
  int pg = tid >> 4, cg = tid & 15;
  int p0 = blockIdx.x * TP;
  int k0 = blockIdx.y * 3;
  float acc[4][CO];
#pragma unroll
  for (int i = 0; i < 4; i++)
#pragma unroll
    for (int j = 0; j < CO; j++) acc[i][j] = 0.f;

  for (int kk = 0; kk < 3; kk++) {
    int k = k0 + kk;
    __syncthreads();
    for (int ch = tid; ch < TP * CIN / 4; ch += 128) {
      int r = ch & (TP - 1), c4 = ch / TP;
      int p = p0 + r;
      int idx = (p < n) ? nbr[(size_t)p * 27 + k] : -1;
      float4 fv = make_float4(0.f, 0.f, 0.f, 0.f);
      if (idx >= 0) fv = *(const float4*)(feats + (size_t)idx * CIN + c4 * 4);
      G[(c4 * 4 + 0) * LDP + r] = fv.x;
      G[(c4 * 4 + 1) * LDP + r] = fv.y;
      G[(c4 * 4 + 2) * LDP + r] = fv.z;
      G[(c4 * 4 + 3) * LDP + r] = fv.w;
    }
    __syncthreads();
    const float* wk = w + (size_t)k * CIN * COUT + cg * CO;
#pragma unroll
    for (int c = 0; c < CIN; c++) {
      float4 g4 = *(const float4*)&G[c * LDP + pg * 4];
      float wv[CO];
      if constexpr (CO == 4)      *(float4*)wv = *(const float4*)(wk + c * COUT);
      else if constexpr (CO == 2) *(float2*)wv = *(const float2*)(wk + c * COUT);
      else                        wv[0] = wk[c * COUT];
      float gp[4] = {g4.x, g4.y, g4.z, g4.w};
#pragma unroll
      for (int i = 0; i < 4; i++)
#pragma unroll
        for (int j = 0; j < CO; j++) acc[i][j] = fmaf(gp[i], wv[j], acc[i][j]);
    }
  }
#pragma unroll
  for (int i = 0; i < 4; i++) {
    int p = p0 + pg * 4 + i;
    if (p < n) {
      float* dst = partial + (size_t)blockIdx.y * gstride + (size_t)p * COUT + cg * CO;
      if constexpr (CO == 4)      *(float4*)dst = *(float4*)acc[i];
      else if constexpr (CO == 2) *(float2*)dst = *(float2*)acc[i];
      else                        dst[0] = acc[i][0];
    }
  }
}

// ---------------- f16 conv: h2 features + h2 weights, v_dot2_f32_f16, fused BN+ReLU ----------------
// CRITICAL: absent neighbor (idx<0) stages ZERO — BN+ReLU must NOT be applied to zeros.
template<int CIN, int COUT>
__global__ __launch_bounds__(128) void convh_k(const unsigned* __restrict__ fh,
                                               const int* __restrict__ nbr,
                                               const unsigned* __restrict__ wh, int n,
                                               float* __restrict__ partial, int gstride,
                                               const float* __restrict__ scsh) {
  constexpr int TP = 32;
  constexpr int LDPH = 36;        // uint row stride (144B, 16B-aligned)
  constexpr int CO = COUT / 16;
  constexpr int CP = CIN / 2;     // channel pairs
  __shared__ unsigned H[CP * LDPH];
  int tid = threadIdx.x;
  int pg = tid >> 4, cg = tid & 15;
  int p0 = blockIdx.x * TP;
  int k0 = blockIdx.y * 3;
  int r = tid & 31;               // this thread stages point r for all its items
  int p = p0 + r;
  float acc[4][CO];
#pragma unroll
  for (int i = 0; i < 4; i++)
#pragma unroll
    for (int j = 0; j < CO; j++) acc[i][j] = 0.f;

  for (int kk = 0; kk < 3; kk++) {
    int k = k0 + kk;
    int idx = (p < n) ? nbr[(size_t)p * 27 + k] : -1;
    bool ok = idx >= 0;
    __syncthreads();
    if constexpr (CIN >= 32) {
      constexpr int NLD = CIN / 32;   // uint4 items per thread
#pragma unroll
      for (int it = 0; it < NLD; it++) {
        int q = (tid >> 5) + it * 4;  // uint4 index in [0, CIN/8)
        uint4 u = make_uint4(0, 0, 0, 0);
        if (ok) u = *(const uint4*)(fh + (size_t)idx * CP + q * 4);
        unsigned uu[4] = {u.x, u.y, u.z, u.w};
#pragma unroll
        for (int j = 0; j < 4; j++) {
          int cp = q * 4 + j;
          unsigned outw = 0;
          if (ok) {
            h2_t h = u2h(uu[j]);
            float lo = fmaxf(fmaf((float)h[0], scsh[2 * cp], scsh[CIN + 2 * cp]), 0.f);
            float hi = fmaxf(fmaf((float)h[1], scsh[2 * cp + 1], scsh[CIN + 2 * cp + 1]), 0.f);
            h2_t o; o[0] = (_Float16)lo; o[1] = (_Float16)hi;
            outw = h2u(o);
          }
          H[cp * LDPH + r] = outw;
        }
      }
    } else {  // CIN == 16: one uint2 per thread
      int q = tid >> 5;               // uint2 index in [0,4)
      uint2 u = make_uint2(0, 0);
      if (ok) u = *(const uint2*)(fh + (size_t)idx * CP + q * 2);
      unsigned uu[2] = {u.x, u.y};
#pragma unroll
      for (int j = 0; j < 2; j++) {
        int cp = q * 2 + j;
        unsigned outw = 0;
        if (ok) {
          h2_t h = u2h(uu[j]);
          float lo = fmaxf(fmaf((float)h[0], scsh[2 * cp], scsh[CIN + 2 * cp]), 0.f);
          float hi = fmaxf(fmaf((float)h[1], scsh[2 * cp + 1], scsh[CIN + 2 * cp + 1]), 0.f);
          h2_t o; o[0] = (_Float16)lo; o[1] = (_Float16)hi;
          outw = h2u(o);
        }
        H[cp * LDPH + r] = outw;
      }
    }
    __syncthreads();
    const unsigned* wk = wh + (size_t)k * CP * COUT + cg * CO;
#pragma unroll 8
    for (int cp = 0; cp < CP; cp++) {
      uint4 g4 = *(const uint4*)&H[cp * LDPH + pg * 4];
      unsigned gg[4] = {g4.x, g4.y, g4.z, g4.w};
      unsigned wv[CO];
      if constexpr (CO == 4)      *(uint4*)wv = *(const uint4*)(wk + cp * COUT);
      else if constexpr (CO == 2) *(uint2*)wv = *(const uint2*)(wk + cp * COUT);
      else                        wv[0] = wk[cp * COUT];
#pragma unroll
      for (int i = 0; i < 4; i++)
#pragma unroll
        for (int j = 0; j < CO; j++)
          acc[i][j] = __builtin_amdgcn_fdot2(u2h(gg[i]), u2h(wv[j]), acc[i][j], false);
    }
  }
#pragma unroll
  for (int i = 0; i < 4; i++) {
    int pp = p0 + pg * 4 + i;
    if (pp < n) {
      float* dst = partial + (size_t)blockIdx.y * gstride + (size_t)pp * COUT + cg * CO;
      if constexpr (CO == 4)      *(float4*)dst = *(float4*)acc[i];
      else if constexpr (CO == 2) *(float2*)dst = *(float2*)acc[i];
      else                        dst[0] = acc[i][0];
    }
  }
}

// ---------------- bn: sum partials -> pre (fp32) + preh (h2) + stats; last block -> (sc, sh) ----------------
__global__ void bn_k(const float* __restrict__ partial, int G, int gstride, int n, int C,
                     float* __restrict__ pre, unsigned* __restrict__ preh,
                     float* __restrict__ stats, const float* __restrict__ bnp,
                     float* __restrict__ scsh, int* __restrict__ ctr) {
  __shared__ float l1e[256], l2e[256], l1o[256], l2o[256];
  __shared__ int lastf;
  int t = threadIdx.x;
  int total = n * C;
  float s1e = 0.f, s2e = 0.f, s1o = 0.f, s2o = 0.f;
  for (int i2 = (blockIdx.x * 256 + t) * 2; i2 < total; i2 += NCH * 512) {
    float v0 = 0.f, v1 = 0.f;
    for (int g = 0; g < G; g++) {
      float2 pv = *(const float2*)(partial + (size_t)g * gstride + i2);
      v0 += pv.x; v1 += pv.y;
    }
    *(float2*)(pre + i2) = make_float2(v0, v1);
    h2_t h; h[0] = (_Float16)v0; h[1] = (_Float16)v1;
    preh[i2 >> 1] = h2u(h);
    s1e += v0; s2e += v0 * v0; s1o += v1; s2o += v1 * v1;
  }
  l1e[t] = s1e; l2e[t] = s2e; l1o[t] = s1o; l2o[t] = s2o;
  for (int s = 128; s >= C / 2; s >>= 1) {
    __syncthreads();
    if (t < s) {
      l1e[t] += l1e[t + s]; l2e[t] += l2e[t + s];
      l1o[t] += l1o[t + s]; l2o[t] += l2o[t + s];
    }
  }
  __syncthreads();
  if (t < C / 2) {
    stats[((size_t)blockIdx.x * C + 2 * t) * 2]     = l1e[t];
    stats[((size_t)blockIdx.x * C + 2 * t) * 2 + 1] = l2e[t];
    stats[((size_t)blockIdx.x * C + 2 * t + 1) * 2]     = l1o[t];
    stats[((size_t)blockIdx.x * C + 2 * t + 1) * 2 + 1] = l2o[t];
  }
  __threadfence();
  __syncthreads();
  if (t == 0) lastf = (atomicAdd(ctr, 1) == NCH - 1) ? 1 : 0;
  __syncthreads();
  if (lastf) {
    __threadfence();
    if (t < C) {
      float a1 = 0.f, a2 = 0.f;
      for (int ch = 0; ch < NCH; ch++) {
        a1 += stats[((size_t)ch * C + t) * 2];
        a2 += stats[((size_t)ch * C + t) * 2 + 1];
      }
      float m = a1 / n;
      float v = a2 / n - m * m;
      float sc = bnp[t] / sqrtf(v + BNEPS);
      scsh[t] = sc;
      scsh[C + t] = bnp[C + t] - m * sc;
    }
  }
}

// ---------------- points_mean ----------------
__global__ void pm_k(const float* __restrict__ vf, const int* __restrict__ c0, int n0,
                     float* __restrict__ pm, float* __restrict__ out1) {
  int i = blockIdx.x * 256 + threadIdx.x;
  if (i >= n0) return;
  float b = (float)c0[(size_t)i * 4];
  float x = vf[(size_t)i * 4], y = vf[(size_t)i * 4 + 1], z = vf[(size_t)i * 4 + 2];
  pm[(size_t)i * 4] = b; pm[(size_t)i * 4 + 1] = x; pm[(size_t)i * 4 + 2] = y; pm[(size_t)i * 4 + 3] = z;
  out1[(size_t)i * 4] = b; out1[(size_t)i * 4 + 1] = x; out1[(size_t)i * 4 + 2] = y; out1[(size_t)i * 4 + 3] = z;
}

// ---------------- knn prep ----------------
__global__ void knnprep_k(const int* __restrict__ coords, int nl, float vx, float vy, float vz,
                          float4* __restrict__ kp4, int* __restrict__ bs) {
  int i = blockIdx.x * 256 + threadIdx.x;
  if (i >= nl) return;
  const int* c = coords + (size_t)i * 4;
  kp4[i] = make_float4(OFFX + (c[3] + 0.5f) * vx,
                       OFFY + (c[2] + 0.5f) * vy,
                       OFFZ + (c[1] + 0.5f) * vz, (float)c[0]);
  if (c[0] == 0 && (i + 1 == nl || coords[(size_t)(i + 1) * 4] == 1)) bs[0] = i + 1;
}

// ---------------- 3-NN: one WAVE per unknown; med3 sorted insert; shfl merge ----------------
__global__ __launch_bounds__(256) void knn_k(const float4* __restrict__ pm4, int n0,
                                             const float4* __restrict__ kp4, int nl,
                                             const int* __restrict__ bsp,
                                             float* __restrict__ wv, int* __restrict__ iv) {
  int wave = threadIdx.x >> 6, lane = threadIdx.x & 63;
  int u = blockIdx.x * 4 + wave;
  if (u >= n0) return;
  float4 up = pm4[u];
  int bs = bsp[0];
  int lo = (up.x == 0.f) ? 0 : bs;
  int hi = (up.x == 0.f) ? bs : nl;
  float ux = up.y, uy = up.z, uz = up.w;
  float d0 = 3e38f, d1 = 3e38f, d2 = 3e38f;
  int i0 = -1, i1 = -1, i2 = -1;
#define INS1(DD, GI) { \
    bool l0 = (DD) < d0, l1 = (DD) < d1, l2 = (DD) < d2; \
    i2 = l2 ? (l1 ? i1 : (GI)) : i2; \
    i1 = l1 ? (l0 ? i0 : (GI)) : i1; \
    i0 = l0 ? (GI) : i0; \
    float t1_ = __builtin_amdgcn_fmed3f(d0, d1, (DD)); \
    float t2_ = __builtin_amdgcn_fmed3f(d1, d2, (DD)); \
    d0 = fminf(d0, (DD)); d1 = t1_; d2 = t2_; }
  for (int e = lo + lane; e < hi; e += 64) {
    float4 q = kp4[e];
    float dx = ux - q.x, dy = uy - q.y, dz = uz - q.z;
    float dd = fmaf(dx, dx, fmaf(dy, dy, dz * dz));
    INS1(dd, e)
  }
#pragma unroll
  for (int off = 1; off < 64; off <<= 1) {
    float e0 = __shfl_xor(d0, off), e1 = __shfl_xor(d1, off), e2 = __shfl_xor(d2, off);
    int j0 = __shfl_xor(i0, off), j1 = __shfl_xor(i1, off), j2 = __shfl_xor(i2, off);
    INS1(e0, j0) INS1(e1, j1) INS1(e2, j2)
  }
#undef INS1
  if (lane == 0) {
    float w0 = 1.f / (d0 + 1e-8f), w1 = 1.f / (d1 + 1e-8f), w2 = 1.f / (d2 + 1e-8f);
    float s = w0 + w1 + w2;
    wv[(size_t)u * 3] = w0 / s; wv[(size_t)u * 3 + 1] = w1 / s; wv[(size_t)u * 3 + 2] = w2 / s;
    iv[(size_t)u * 3] = i0; iv[(size_t)u * 3 + 1] = i1; iv[(size_t)u * 3 + 2] = i2;
  }
}

// interp with fused BN+ReLU on source features (f = PRE fp32, scsh of source layer)
__global__ void interp_k(const float* __restrict__ f, int C, const float* __restrict__ scsh,
                         const float* __restrict__ wv, const int* __restrict__ iv, int n0,
                         float* __restrict__ X, int xoff) {
  int t = blockIdx.x * 256 + threadIdx.x;
  if (t >= n0 * C) return;
  int u = t / C, c = t % C;
  float sc = scsh[c], sh = scsh[C + c];
  float a0 = fmaxf(fmaf(f[(size_t)iv[(size_t)u * 3]     * C + c], sc, sh), 0.f);
  float a1 = fmaxf(fmaf(f[(size_t)iv[(size_t)u * 3 + 1] * C + c], sc, sh), 0.f);
  float a2 = fmaxf(fmaf(f[(size_t)iv[(size_t)u * 3 + 2] * C + c], sc, sh), 0.f);
  X[(size_t)u * 160 + xoff + c] = wv[(size_t)u * 3] * a0 + wv[(size_t)u * 3 + 1] * a1
                                + wv[(size_t)u * 3 + 2] * a2;
}

// ---------------- extra 1x1 conv with fused input BN ----------------
__global__ __launch_bounds__(256) void conv1x1_k(const float* __restrict__ f,
                                                 const float* __restrict__ scsh,
                                                 const float* __restrict__ we, int n,
                                                 float* __restrict__ out) {
  __shared__ float rows[256];
  int t = threadIdx.x;
  int p = blockIdx.x * 4 + (t >> 6), c = t & 63;
  rows[t] = (p < n) ? fmaxf(fmaf(f[(size_t)p * 64 + c], scsh[c], scsh[64 + c]), 0.f) : 0.f;
  __syncthreads();
  if (p >= n) return;
  const float* fr = rows + (t >> 6) * 64;
  float a = 0.f;
#pragma unroll 16
  for (int ci = 0; ci < 64; ci++) a = fmaf(fr[ci], we[ci * 64 + c], a);
  out[(size_t)p * 64 + c] = a;
}

// ---------------- dense scatter with fused BN+ReLU ----------------
__global__ void scatter_k(const float* __restrict__ pre, const float* __restrict__ scsh,
                          const int* __restrict__ c3, int n3, float* __restrict__ out0) {
  int t = blockIdx.x * 256 + threadIdx.x;
  if (t >= n3 * 64) return;
  int p = t >> 6, c = t & 63;
  const int* cc = c3 + (size_t)p * 4;
  size_t o = ((((size_t)cc[0] * 64 + c) * 6 + cc[1]) * 100 + cc[2]) * 100 + cc[3];
  out0[o] = fmaxf(fmaf(pre[t], scsh[c], scsh[64 + c]), 0.f);
}

// ---------------- head ----------------
__global__ __launch_bounds__(256) void head_k(const float* __restrict__ X,
                                              const float* __restrict__ fcw,
                                              const float* __restrict__ clsw,
                                              const float* __restrict__ regw,
                                              int n0, float* __restrict__ outc,
                                              float* __restrict__ outr) {
  __shared__ float fl[64 * 161];
  int t = threadIdx.x;
  for (int i = t; i < 64 * 160; i += 256) {
    int r = i / 160, c = i % 160;
    fl[r * 161 + c] = fcw[i];
  }
  __syncthreads();
  int wave = t >> 6, lane = t & 63;
  int u = blockIdx.x * 4 + wave;
  if (u >= n0) return;
  const float* xr = X + (size_t)u * 160;
  const float* wr = fl + (size_t)lane * 161;
  float a = 0.f;
#pragma unroll 8
  for (int i = 0; i < 160; i++) a = fmaf(xr[i], wr[i], a);
  float c = a * clsw[lane];
  float r0 = a * regw[lane], r1 = a * regw[64 + lane], r2 = a * regw[128 + lane];
  for (int off = 32; off; off >>= 1) {
    c  += __shfl_down(c, off);
    r0 += __shfl_down(r0, off);
    r1 += __shfl_down(r1, off);
    r2 += __shfl_down(r2, off);
  }
  if (lane == 0) {
    outc[u] = c;
    outr[(size_t)u * 3] = r0; outr[(size_t)u * 3 + 1] = r1; outr[(size_t)u * 3 + 2] = r2;
  }
}

// ---------------- host ----------------
extern "C" void kernel_launch(void* const* d_in, const int* in_sizes, int n_in,
                              void* d_out, int out_size, void* d_ws, size_t ws_size,
                              hipStream_t stream) {
  const float* vf  = (const float*)d_in[0];
  const int* c0 = (const int*)d_in[1];
  const int* c1 = (const int*)d_in[2];
  const int* c2 = (const int*)d_in[3];
  const int* c3 = (const int*)d_in[4];
  const float* w00 = (const float*)d_in[5];  const float* b00 = (const float*)d_in[6];
  const float* w01 = (const float*)d_in[7];  const float* b01 = (const float*)d_in[8];
  const float* wd0 = (const float*)d_in[9];  const float* bd0 = (const float*)d_in[10];
  const float* w10 = (const float*)d_in[11]; const float* b10 = (const float*)d_in[12];
  const float* w11 = (const float*)d_in[13]; const float* b11 = (const float*)d_in[14];
  const float* wd1 = (const float*)d_in[15]; const float* bd1 = (const float*)d_in[16];
  const float* w20 = (const float*)d_in[17]; const float* b20 = (const float*)d_in[18];
  const float* w21 = (const float*)d_in[19]; const float* b21 = (const float*)d_in[20];
  const float* w22 = (const float*)d_in[21]; const float* b22 = (const float*)d_in[22];
  const float* wd2 = (const float*)d_in[23]; const float* bd2 = (const float*)d_in[24];
  const float* w30 = (const float*)d_in[25]; const float* b30 = (const float*)d_in[26];
  const float* w31 = (const float*)d_in[27]; const float* b31 = (const float*)d_in[28];
  const float* w32 = (const float*)d_in[29]; const float* b32 = (const float*)d_in[30];
  const float* we  = (const float*)d_in[31]; const float* be  = (const float*)d_in[32];
  const float* fcw = (const float*)d_in[33];
  const float* clsw = (const float*)d_in[34];
  const float* regw = (const float*)d_in[35];

  int N0 = in_sizes[1] / 4, N1 = in_sizes[2] / 4, N2 = in_sizes[3] / 4, N3 = in_sizes[4] / 4;
  int maxN = N0; if (N1 > maxN) maxN = N1; if (N2 > maxN) maxN = N2; if (N3 > maxN) maxN = N3;

  auto cdiv = [](int a, int b) { return (a + b - 1) / b; };
  char* p = (char*)d_ws;
  auto alloc = [&](size_t bytes) { char* r = p; p += (bytes + 255) & ~(size_t)255; return r; };

  int* keys0 = (int*)alloc((size_t)N0 * 4);
  int* keys1 = (int*)alloc((size_t)N1 * 4);
  int* keys2 = (int*)alloc((size_t)N2 * 4);
  int* keys3 = (int*)alloc((size_t)N3 * 4);
  int* nbr0  = (int*)alloc((size_t)N0 * 27 * 4);
  int* nbrs1 = (int*)alloc((size_t)N1 * 27 * 4);
  int* nbr1  = (int*)alloc((size_t)N1 * 27 * 4);
  int* nbrs2 = (int*)alloc((size_t)N2 * 27 * 4);
  int* nbr2  = (int*)alloc((size_t)N2 * 27 * 4);
  int* nbrs3 = (int*)alloc((size_t)N3 * 27 * 4);
  int* nbr3  = (int*)alloc((size_t)N3 * 27 * 4);
  float* FA = (float*)alloc((size_t)maxN * 64 * 4);
  float* FB = (float*)alloc((size_t)maxN * 64 * 4);
  float* FC = (float*)alloc((size_t)maxN * 64 * 4);
  unsigned* FAh = (unsigned*)alloc((size_t)maxN * 32 * 4);
  unsigned* FBh = (unsigned*)alloc((size_t)maxN * 32 * 4);
  float* stats = (float*)alloc((size_t)NCH * 64 * 2 * 4);
  float* SC = (float*)alloc((size_t)15 * 128 * 4);
  int* ctrs = (int*)alloc(16 * 4);
  float* wv = (float*)alloc((size_t)N0 * 3 * 4);
  int*   iv = (int*)alloc((size_t)N0 * 3 * 4);
  float* X  = (float*)alloc((size_t)N0 * 160 * 4);
  float* pmb = (float*)alloc((size_t)N0 * 4 * 4);
  float4* kp1 = (float4*)alloc((size_t)N1 * 16);
  float4* kp2 = (float4*)alloc((size_t)N2 * 16);
  float4* kp3 = (float4*)alloc((size_t)N3 * 16);
  int* bsA = (int*)alloc(32);
  unsigned* whbuf = (unsigned*)alloc((size_t)452736 * 4);  // packed h2 weights, all layers

  float* out0 = (float*)d_out;
  float* out1 = out0 + 7680000;
  float* outc = out1 + (size_t)N0 * 4;
  float* outr = outc + N0;
  float* partial = out0;  // conv partial scratch until final memset

  auto scsh = [&](int L) { return SC + (size_t)L * 128; };

  // ---- packed-weight offsets (uints) ----
  const float* wsrc[13] = {w01, wd0, w10, w11, wd1, w20, w21, w22, wd2, w30, w31, w32, nullptr};
  int wcin[13]  = {16, 16, 32, 32, 32, 64, 64, 64, 64, 64, 64, 64, 0};
  int wcout[13] = {16, 32, 32, 32, 64, 64, 64, 64, 64, 64, 64, 64, 0};
  unsigned* wdst[13];
  size_t woff = 0;
  WP13 wp{};
  int nw = 12;
  for (int i = 0; i < nw; i++) {
    wdst[i] = whbuf + woff;
    wp.l[i] = WPrep{wsrc[i], wdst[i], wcin[i], wcout[i]};
    woff += (size_t)27 * (wcin[i] / 2) * wcout[i];
  }
  for (int i = nw; i < 13; i++) wp.l[i] = WPrep{w01, wdst[0], 16, 16};  // pad (unused)

  hipMemsetAsync(ctrs, 0, 16 * 4, stream);
  wprep_k<<<dim3(216, nw), 256, 0, stream>>>(wp);
  keys_k<<<cdiv(N0, 256), 256, 0, stream>>>(c0, N0, 41, 800, 800, keys0);
  keys_k<<<cdiv(N1, 256), 256, 0, stream>>>(c1, N1, 21, 400, 400, keys1);
  keys_k<<<cdiv(N2, 256), 256, 0, stream>>>(c2, N2, 11, 200, 200, keys2);
  keys_k<<<cdiv(N3, 256), 256, 0, stream>>>(c3, N3, 6, 100, 100, keys3);
  nbr_k<<<cdiv(N0 * 27, 256), 256, 0, stream>>>(c0, N0, keys0, N0, 41, 800, 800, 1, nbr0);
  nbr_k<<<cdiv(N1 * 27, 256), 256, 0, stream>>>(c1, N1, keys0, N0, 41, 800, 800, 2, nbrs1);
  nbr_k<<<cdiv(N1 * 27, 256), 256, 0, stream>>>(c1, N1, keys1, N1, 21, 400, 400, 1, nbr1);
  nbr_k<<<cdiv(N2 * 27, 256), 256, 0, stream>>>(c2, N2, keys1, N1, 21, 400, 400, 2, nbrs2);
  nbr_k<<<cdiv(N2 * 27, 256), 256, 0, stream>>>(c2, N2, keys2, N2, 11, 200, 200, 1, nbr2);
  nbr_k<<<cdiv(N3 * 27, 256), 256, 0, stream>>>(c3, N3, keys2, N2, 11, 200, 200, 2, nbrs3);
  nbr_k<<<cdiv(N3 * 27, 256), 256, 0, stream>>>(c3, N3, keys3, N3, 6, 100, 100, 1, nbr3);
  pm_k<<<cdiv(N0, 256), 256, 0, stream>>>(vf, c0, N0, pmb, out1);
  knnprep_k<<<cdiv(N1, 256), 256, 0, stream>>>(c1, N1, 0.2f, 0.2f, 0.4f, kp1, bsA + 0);
  knnprep_k<<<cdiv(N2, 256), 256, 0, stream>>>(c2, N2, 0.4f, 0.4f, 0.8f, kp2, bsA + 1);
  knnprep_k<<<cdiv(N3, 256), 256, 0, stream>>>(c3, N3, 0.8f, 0.8f, 1.6f, kp3, bsA + 2);

  auto convh = [&](const unsigned* fhin, const int* nb, int wi, int n, int cin, int cout,
                   const float* ss) {
    dim3 g(cdiv(n, 32), NG);
    int gs = n * cout;
    const unsigned* wh = wdst[wi];
    if (cin == 16 && cout == 16)
      convh_k<16, 16><<<g, 128, 0, stream>>>(fhin, nb, wh, n, partial, gs, ss);
    else if (cin == 16 && cout == 32)
      convh_k<16, 32><<<g, 128, 0, stream>>>(fhin, nb, wh, n, partial, gs, ss);
    else if (cin == 32 && cout == 32)
      convh_k<32, 32><<<g, 128, 0, stream>>>(fhin, nb, wh, n, partial, gs, ss);
    else if (cin == 32 && cout == 64)
      convh_k<32, 64><<<g, 128, 0, stream>>>(fhin, nb, wh, n, partial, gs, ss);
    else
      convh_k<64, 64><<<g, 128, 0, stream>>>(fhin, nb, wh, n, partial, gs, ss);
  };
  auto bnp = [&](const float* bnpar, int n, int C, float* pre, unsigned* preh, int L) {
    bn_k<<<NCH, 256, 0, stream>>>(partial, NG, n * C, n, C, pre, preh, stats, bnpar,
                                  scsh(L), ctrs + L);
  };
  auto knn = [&](const float4* kp4, const int* bsl, int nl, const float* f, int C, int L,
                 int xoff) {
    knn_k<<<cdiv(N0, 4), 256, 0, stream>>>((const float4*)pmb, N0, kp4, nl, bsl, wv, iv);
    interp_k<<<cdiv(N0 * C, 256), 256, 0, stream>>>(f, C, scsh(L), wv, iv, N0, X, xoff);
  };

  // layer 0: fp32 conv from raw voxel features
  convg_k<4, 16><<<dim3(cdiv(N0, 32), NG), 128, 0, stream>>>(vf, nbr0, w00, N0, partial, N0 * 16);
  bnp(b00, N0, 16, FA, FAh, 0);
  convh(FAh, nbr0, 0, N0, 16, 16, scsh(0));   bnp(b01, N0, 16, FB, FBh, 1);
  convh(FBh, nbrs1, 1, N1, 16, 32, scsh(1));  bnp(bd0, N1, 32, FA, FAh, 2);
  convh(FAh, nbr1, 2, N1, 32, 32, scsh(2));   bnp(b10, N1, 32, FB, FBh, 3);
  convh(FBh, nbr1, 3, N1, 32, 32, scsh(3));   bnp(b11, N1, 32, FA, FAh, 4);
  knn(kp1, bsA + 0, N1, FA, 32, 4, 0);
  convh(FAh, nbrs2, 4, N2, 32, 64, scsh(4));  bnp(bd1, N2, 64, FB, FBh, 5);
  convh(FBh, nbr2, 5, N2, 64, 64, scsh(5));   bnp(b20, N2, 64, FA, FAh, 6);
  convh(FAh, nbr2, 6, N2, 64, 64, scsh(6));   bnp(b21, N2, 64, FB, FBh, 7);
  convh(FBh, nbr2, 7, N2, 64, 64, scsh(7));   bnp(b22, N2, 64, FA, FAh, 8);
  knn(kp2, bsA + 1, N2, FA, 64, 8, 32);
  convh(FAh, nbrs3, 8, N3, 64, 64, scsh(8));  bnp(bd2, N3, 64, FB, FBh, 9);
  convh(FBh, nbr3, 9, N3, 64, 64, scsh(9));   bnp(b30, N3, 64, FA, FAh, 10);
  convh(FAh, nbr3, 10, N3, 64, 64, scsh(10)); bnp(b31, N3, 64, FB, FBh, 11);
  convh(FBh, nbr3, 11, N3, 64, 64, scsh(11)); bnp(b32, N3, 64, FA, FAh, 12);
  knn(kp3, bsA + 2, N3, FA, 64, 12, 96);

  conv1x1_k<<<cdiv(N3, 4), 256, 0, stream>>>(FA, scsh(12), we, N3, FC);
  bn_k<<<NCH, 256, 0, stream>>>(FC, 1, 0, N3, 64, FB, FBh, stats, be, scsh(13), ctrs + 13);
  hipMemsetAsync(d_out, 0, (size_t)7680000 * 4, stream);
  scatter_k<<<cdiv(N3 * 64, 256), 256, 0, stream>>>(FB, scsh(13), c3, N3, out0);
  head_k<<<cdiv(N0, 4), 256, 0, stream>>>(X, fcw, clsw, regw, N0, outc, outr);
}

// Round 14
// 923.486 us; speedup vs baseline: 1.4176x; 1.0414x over previous
//
#include <hip/hip_runtime.h>

#define OFFX 0.0f
#define OFFY -40.0f
#define OFFZ -3.0f
#define BNEPS 1e-3f
#define NCH 128   // bn partial chunks
#define NG 9      // conv tap groups (3 taps each)

typedef _Float16 h2_t __attribute__((ext_vector_type(2)));
__device__ inline h2_t u2h(unsigned u) { union { unsigned u; h2_t h; } x; x.u = u; return x.h; }
__device__ inline unsigned h2u(h2_t h) { union { unsigned u; h2_t h; } x; x.h = h; return x.u; }

// ---------------- keys ----------------
__global__ void keys_k(const int* __restrict__ coords, int n, int D, int H, int W,
                       int* __restrict__ keys) {
  int i = blockIdx.x * 256 + threadIdx.x;
  if (i < n) {
    const int* c = coords + (size_t)i * 4;
    keys[i] = ((c[0] * D + c[1]) * H + c[2]) * W + c[3];
  }
}

// ---------------- neighbor tables ----------------
__global__ void nbr_k(const int* __restrict__ coords, int np, const int* __restrict__ keys, int nk,
                      int D, int H, int W, int scale, int* __restrict__ nbr) {
  int t = blockIdx.x * 256 + threadIdx.x;
  if (t >= np * 27) return;
  int p = t / 27, k = t % 27;
  int kz = k / 9 - 1, ky = (k / 3) % 3 - 1, kx = k % 3 - 1;
  const int* c = coords + (size_t)p * 4;
  int z = c[1] * scale + kz, y = c[2] * scale + ky, x = c[3] * scale + kx;
  int r = -1;
  if (z >= 0 && z < D && y >= 0 && y < H && x >= 0 && x < W) {
    int q = ((c[0] * D + z) * H + y) * W + x;
    int lo = 0, hi = nk;
    while (lo < hi) { int m = (lo + hi) >> 1; if (keys[m] < q) lo = m + 1; else hi = m; }
    if (lo < nk && keys[lo] == q) r = lo;
  }
  nbr[t] = r;
}

// ---------------- weight prep: fp32 [27][CIN][COUT] -> h2 [27][CIN/2][COUT] ----------------
struct WPrep { const float* src; unsigned* dst; int cin; int cout; };
struct WP13 { WPrep l[13]; };
__global__ void wprep_k(WP13 a) {
  WPrep w = a.l[blockIdx.y];
  int cp2 = w.cin / 2;
  int tot = 27 * cp2 * w.cout;
  int i = blockIdx.x * 256 + threadIdx.x;
  if (i >= tot) return;
  int o = i % w.cout, rest = i / w.cout;
  int cp = rest % cp2, k = rest / cp2;
  float lo = w.src[((size_t)k * w.cin + 2 * cp) * w.cout + o];
  float hi = w.src[((size_t)k * w.cin + 2 * cp + 1) * w.cout + o];
  h2_t h; h[0] = (_Float16)lo; h[1] = (_Float16)hi;
  w.dst[i] = h2u(h);
}

// ---------------- layer-0 conv (fp32, CIN=4): LDS tile-GEMM TP=32 ----------------
template<int CIN, int COUT>
__global__ __launch_bounds__(128) void convg_k(const float* __restrict__ feats,
                                               const int* __restrict__ nbr,
                                               const float* __restrict__ w, int n,
                                               float* __restrict__ partial, int gstride) {
  constexpr int TP = 32;
  constexpr int LDP = 36;
  constexpr int CO = COUT / 16;
  __shared__ float G[CIN * LDP];
  int tid = threadIdx.x;
  int pg = tid >> 4, cg = tid & 15;
  int p0 = blockIdx.x * TP;
  int k0 = blockIdx.y * 3;
  float acc[4][CO];
#pragma unroll
  for (int i = 0; i < 4; i++)
#pragma unroll
    for (int j = 0; j < CO; j++) acc[i][j] = 0.f;

  for (int kk = 0; kk < 3; kk++) {
    int k = k0 + kk;
    __syncthreads();
    for (int ch = tid; ch < TP * CIN / 4; ch += 128) {
      int r = ch & (TP - 1), c4 = ch / TP;
      int p = p0 + r;
      int idx = (p < n) ? nbr[(size_t)p * 27 + k] : -1;
      float4 fv = make_float4(0.f, 0.f, 0.f, 0.f);
      if (idx >= 0) fv = *(const float4*)(feats + (size_t)idx * CIN + c4 * 4);
      G[(c4 * 4 + 0) * LDP + r] = fv.x;
      G[(c4 * 4 + 1) * LDP + r] = fv.y;
      G[(c4 * 4 + 2) * LDP + r] = fv.z;
      G[(c4 * 4 + 3) * LDP + r] = fv.w;
    }
    __syncthreads();
    const float* wk = w + (size_t)k * CIN * COUT + cg * CO;
#pragma unroll
    for (int c = 0; c < CIN; c++) {
      float4 g4 = *(const float4*)&G[c * LDP + pg * 4];
      float wv[CO];
      if constexpr (CO == 4)      *(float4*)wv = *(const float4*)(wk + c * COUT);
      else if constexpr (CO == 2) *(float2*)wv = *(const float2*)(wk + c * COUT);
      else                        wv[0] = wk[c * COUT];
      float gp[4] = {g4.x, g4.y, g4.z, g4.w};
#pragma unroll
      for (int i = 0; i < 4; i++)
#pragma unroll
        for (int j = 0; j < CO; j++) acc[i][j] = fmaf(gp[i], wv[j], acc[i][j]);
    }
  }
#pragma unroll
  for (int i = 0; i < 4; i++) {
    int p = p0 + pg * 4 + i;
    if (p < n) {
      float* dst = partial + (size_t)blockIdx.y * gstride + (size_t)p * COUT + cg * CO;
      if constexpr (CO == 4)      *(float4*)dst = *(float4*)acc[i];
      else if constexpr (CO == 2) *(float2*)dst = *(float2*)acc[i];
      else                        dst[0] = acc[i][0];
    }
  }
}

// ---------------- f16 conv: h2 features + h2 weights, v_dot2_f32_f16, fused BN+ReLU ----------------
// absent neighbor (idx<0) stages ZERO — BN+ReLU NOT applied to zeros.
template<int CIN, int COUT>
__global__ __launch_bounds__(128) void convh_k(const unsigned* __restrict__ fh,
                                               const int* __restrict__ nbr,
                                               const unsigned* __restrict__ wh, int n,
                                               float* __restrict__ partial, int gstride,
                                               const float* __restrict__ scsh) {
  constexpr int TP = 32;
  constexpr int LDPH = 36;
  constexpr int CO = COUT / 16;
  constexpr int CP = CIN / 2;
  __shared__ unsigned H[CP * LDPH];
  int tid = threadIdx.x;
  int pg = tid >> 4, cg = tid & 15;
  int p0 = blockIdx.x * TP;
  int k0 = blockIdx.y * 3;
  int r = tid & 31;
  int p = p0 + r;
  float acc[4][CO];
#pragma unroll
  for (int i = 0; i < 4; i++)
#pragma unroll
    for (int j = 0; j < CO; j++) acc[i][j] = 0.f;

  for (int kk = 0; kk < 3; kk++) {
    int k = k0 + kk;
    int idx = (p < n) ? nbr[(size_t)p * 27 + k] : -1;
    bool ok = idx >= 0;
    __syncthreads();
    if constexpr (CIN >= 32) {
      constexpr int NLD = CIN / 32;
#pragma unroll
      for (int it = 0; it < NLD; it++) {
        int q = (tid >> 5) + it * 4;
        uint4 u = make_uint4(0, 0, 0, 0);
        if (ok) u = *(const uint4*)(fh + (size_t)idx * CP + q * 4);
        unsigned uu[4] = {u.x, u.y, u.z, u.w};
#pragma unroll
        for (int j = 0; j < 4; j++) {
          int cp = q * 4 + j;
          unsigned outw = 0;
          if (ok) {
            h2_t h = u2h(uu[j]);
            float lo = fmaxf(fmaf((float)h[0], scsh[2 * cp], scsh[CIN + 2 * cp]), 0.f);
            float hi = fmaxf(fmaf((float)h[1], scsh[2 * cp + 1], scsh[CIN + 2 * cp + 1]), 0.f);
            h2_t o; o[0] = (_Float16)lo; o[1] = (_Float16)hi;
            outw = h2u(o);
          }
          H[cp * LDPH + r] = outw;
        }
      }
    } else {
      int q = tid >> 5;
      uint2 u = make_uint2(0, 0);
      if (ok) u = *(const uint2*)(fh + (size_t)idx * CP + q * 2);
      unsigned uu[2] = {u.x, u.y};
#pragma unroll
      for (int j = 0; j < 2; j++) {
        int cp = q * 2 + j;
        unsigned outw = 0;
        if (ok) {
          h2_t h = u2h(uu[j]);
          float lo = fmaxf(fmaf((float)h[0], scsh[2 * cp], scsh[CIN + 2 * cp]), 0.f);
          float hi = fmaxf(fmaf((float)h[1], scsh[2 * cp + 1], scsh[CIN + 2 * cp + 1]), 0.f);
          h2_t o; o[0] = (_Float16)lo; o[1] = (_Float16)hi;
          outw = h2u(o);
        }
        H[cp * LDPH + r] = outw;
      }
    }
    __syncthreads();
    const unsigned* wk = wh + (size_t)k * CP * COUT + cg * CO;
#pragma unroll 8
    for (int cp = 0; cp < CP; cp++) {
      uint4 g4 = *(const uint4*)&H[cp * LDPH + pg * 4];
      unsigned gg[4] = {g4.x, g4.y, g4.z, g4.w};
      unsigned wv[CO];
      if constexpr (CO == 4)      *(uint4*)wv = *(const uint4*)(wk + cp * COUT);
      else if constexpr (CO == 2) *(uint2*)wv = *(const uint2*)(wk + cp * COUT);
      else                        wv[0] = wk[cp * COUT];
#pragma unroll
      for (int i = 0; i < 4; i++)
#pragma unroll
        for (int j = 0; j < CO; j++)
          acc[i][j] = __builtin_amdgcn_fdot2(u2h(gg[i]), u2h(wv[j]), acc[i][j], false);
    }
  }
#pragma unroll
  for (int i = 0; i < 4; i++) {
    int pp = p0 + pg * 4 + i;
    if (pp < n) {
      float* dst = partial + (size_t)blockIdx.y * gstride + (size_t)pp * COUT + cg * CO;
      if constexpr (CO == 4)      *(float4*)dst = *(float4*)acc[i];
      else if constexpr (CO == 2) *(float2*)dst = *(float2*)acc[i];
      else                        dst[0] = acc[i][0];
    }
  }
}

// ---------------- bn: sum partials -> pre(opt fp32) + preh (h2) + stats; last block -> (sc, sh) ----------------
__global__ void bn_k(const float* __restrict__ partial, int G, int gstride, int n, int C,
                     float* __restrict__ pre, unsigned* __restrict__ preh,
                     float* __restrict__ stats, const float* __restrict__ bnp,
                     float* __restrict__ scsh, int* __restrict__ ctr) {
  __shared__ float l1e[256], l2e[256], l1o[256], l2o[256];
  __shared__ int lastf;
  int t = threadIdx.x;
  int total = n * C;
  float s1e = 0.f, s2e = 0.f, s1o = 0.f, s2o = 0.f;
  for (int i2 = (blockIdx.x * 256 + t) * 2; i2 < total; i2 += NCH * 512) {
    float v0 = 0.f, v1 = 0.f;
    for (int g = 0; g < G; g++) {
      float2 pv = *(const float2*)(partial + (size_t)g * gstride + i2);
      v0 += pv.x; v1 += pv.y;
    }
    if (pre) *(float2*)(pre + i2) = make_float2(v0, v1);
    h2_t h; h[0] = (_Float16)v0; h[1] = (_Float16)v1;
    preh[i2 >> 1] = h2u(h);
    s1e += v0; s2e += v0 * v0; s1o += v1; s2o += v1 * v1;
  }
  l1e[t] = s1e; l2e[t] = s2e; l1o[t] = s1o; l2o[t] = s2o;
  for (int s = 128; s >= C / 2; s >>= 1) {
    __syncthreads();
    if (t < s) {
      l1e[t] += l1e[t + s]; l2e[t] += l2e[t + s];
      l1o[t] += l1o[t + s]; l2o[t] += l2o[t + s];
    }
  }
  __syncthreads();
  if (t < C / 2) {
    stats[((size_t)blockIdx.x * C + 2 * t) * 2]     = l1e[t];
    stats[((size_t)blockIdx.x * C + 2 * t) * 2 + 1] = l2e[t];
    stats[((size_t)blockIdx.x * C + 2 * t + 1) * 2]     = l1o[t];
    stats[((size_t)blockIdx.x * C + 2 * t + 1) * 2 + 1] = l2o[t];
  }
  __threadfence();
  __syncthreads();
  if (t == 0) lastf = (atomicAdd(ctr, 1) == NCH - 1) ? 1 : 0;
  __syncthreads();
  if (lastf) {
    __threadfence();
    if (t < C) {
      float a1 = 0.f, a2 = 0.f;
      for (int ch = 0; ch < NCH; ch++) {
        a1 += stats[((size_t)ch * C + t) * 2];
        a2 += stats[((size_t)ch * C + t) * 2 + 1];
      }
      float m = a1 / n;
      float v = a2 / n - m * m;
      float sc = bnp[t] / sqrtf(v + BNEPS);
      scsh[t] = sc;
      scsh[C + t] = bnp[C + t] - m * sc;
    }
  }
}

// ---------------- points_mean ----------------
__global__ void pm_k(const float* __restrict__ vf, const int* __restrict__ c0, int n0,
                     float* __restrict__ pm, float* __restrict__ out1) {
  int i = blockIdx.x * 256 + threadIdx.x;
  if (i >= n0) return;
  float b = (float)c0[(size_t)i * 4];
  float x = vf[(size_t)i * 4], y = vf[(size_t)i * 4 + 1], z = vf[(size_t)i * 4 + 2];
  pm[(size_t)i * 4] = b; pm[(size_t)i * 4 + 1] = x; pm[(size_t)i * 4 + 2] = y; pm[(size_t)i * 4 + 3] = z;
  out1[(size_t)i * 4] = b; out1[(size_t)i * 4 + 1] = x; out1[(size_t)i * 4 + 2] = y; out1[(size_t)i * 4 + 3] = z;
}

// ---------------- knn prep ----------------
__global__ void knnprep_k(const int* __restrict__ coords, int nl, float vx, float vy, float vz,
                          float4* __restrict__ kp4, int* __restrict__ bs) {
  int i = blockIdx.x * 256 + threadIdx.x;
  if (i >= nl) return;
  const int* c = coords + (size_t)i * 4;
  kp4[i] = make_float4(OFFX + (c[3] + 0.5f) * vx,
                       OFFY + (c[2] + 0.5f) * vy,
                       OFFZ + (c[1] + 0.5f) * vz, (float)c[0]);
  if (c[0] == 0 && (i + 1 == nl || coords[(size_t)(i + 1) * 4] == 1)) bs[0] = i + 1;
}

// ---------------- 3-NN: 4 waves/block share LDS-staged candidate chunks; wave per unknown;
// per-lane med3 top-3 (same stride-64 traversal order as before); shfl butterfly merge ----------------
__global__ __launch_bounds__(256) void knn_k(const float4* __restrict__ pm4, int n0,
                                             const float4* __restrict__ kp4, int nl,
                                             const int* __restrict__ bsp,
                                             float* __restrict__ wv, int* __restrict__ iv) {
  __shared__ __align__(16) float4 kp[256];
  __shared__ int bl[4], bh[4];
  int tid = threadIdx.x;
  int wave = tid >> 6, lane = tid & 63;
  int u = blockIdx.x * 4 + wave;
  bool valid = u < n0;
  float4 up = pm4[valid ? u : (n0 - 1)];
  int bs = bsp[0];
  int lo = (up.x == 0.f) ? 0 : bs;
  int hi = (up.x == 0.f) ? bs : nl;
  if (!valid) { lo = 0; hi = 0; }
  if (lane == 0) { bl[wave] = valid ? lo : 0x7fffffff; bh[wave] = valid ? hi : 0; }
  __syncthreads();
  int blo = min(min(bl[0], bl[1]), min(bl[2], bl[3]));
  int bhi = max(max(bh[0], bh[1]), max(bh[2], bh[3]));
  float ux = up.y, uy = up.z, uz = up.w;
  float d0 = 3e38f, d1 = 3e38f, d2 = 3e38f;
  int i0 = -1, i1 = -1, i2 = -1;
#define INS1(DD, GI) { \
    bool l0 = (DD) < d0, l1 = (DD) < d1, l2 = (DD) < d2; \
    i2 = l2 ? (l1 ? i1 : (GI)) : i2; \
    i1 = l1 ? (l0 ? i0 : (GI)) : i1; \
    i0 = l0 ? (GI) : i0; \
    float t1_ = __builtin_amdgcn_fmed3f(d0, d1, (DD)); \
    float t2_ = __builtin_amdgcn_fmed3f(d1, d2, (DD)); \
    d0 = fminf(d0, (DD)); d1 = t1_; d2 = t2_; }
#define DIST(Q) fmaf(ux - (Q).x, ux - (Q).x, fmaf(uy - (Q).y, uy - (Q).y, (uz - (Q).z) * (uz - (Q).z)))
  for (int cb = blo; cb < bhi; cb += 256) {
    int m = bhi - cb; if (m > 256) m = 256;
    __syncthreads();
    if (tid < m) kp[tid] = kp4[cb + tid];
    __syncthreads();
    if (cb + 256 <= lo || cb >= hi) continue;  // wave-uniform skip (other batch)
    if (m == 256 && cb >= lo && cb + 256 <= hi) {
      // fast path: whole chunk in this wave's range
      float4 q0 = kp[lane], q1 = kp[lane + 64], q2 = kp[lane + 128], q3 = kp[lane + 192];
      float a0 = DIST(q0), a1 = DIST(q1), a2 = DIST(q2), a3 = DIST(q3);
      INS1(a0, cb + lane) INS1(a1, cb + lane + 64) INS1(a2, cb + lane + 128) INS1(a3, cb + lane + 192)
    } else {
#pragma unroll
      for (int j = 0; j < 4; j++) {
        int i = lane + 64 * j;
        int e = cb + i;
        if (i < m && e >= lo && e < hi) {
          float4 q = kp[i];
          float dd = DIST(q);
          INS1(dd, e)
        }
      }
    }
  }
  // butterfly merge of 64 local top-3 triples
#pragma unroll
  for (int off = 1; off < 64; off <<= 1) {
    float e0 = __shfl_xor(d0, off), e1 = __shfl_xor(d1, off), e2 = __shfl_xor(d2, off);
    int j0 = __shfl_xor(i0, off), j1 = __shfl_xor(i1, off), j2 = __shfl_xor(i2, off);
    INS1(e0, j0) INS1(e1, j1) INS1(e2, j2)
  }
#undef DIST
#undef INS1
  if (valid && lane == 0) {
    float w0 = 1.f / (d0 + 1e-8f), w1 = 1.f / (d1 + 1e-8f), w2 = 1.f / (d2 + 1e-8f);
    float s = w0 + w1 + w2;
    wv[(size_t)u * 3] = w0 / s; wv[(size_t)u * 3 + 1] = w1 / s; wv[(size_t)u * 3 + 2] = w2 / s;
    iv[(size_t)u * 3] = i0; iv[(size_t)u * 3 + 1] = i1; iv[(size_t)u * 3 + 2] = i2;
  }
}

// interp with fused BN+ReLU on source features (f = PRE fp32, scsh of source layer)
__global__ void interp_k(const float* __restrict__ f, int C, const float* __restrict__ scsh,
                         const float* __restrict__ wv, const int* __restrict__ iv, int n0,
                         float* __restrict__ X, int xoff) {
  int t = blockIdx.x * 256 + threadIdx.x;
  if (t >= n0 * C) return;
  int u = t / C, c = t % C;
  float sc = scsh[c], sh = scsh[C + c];
  float a0 = fmaxf(fmaf(f[(size_t)iv[(size_t)u * 3]     * C + c], sc, sh), 0.f);
  float a1 = fmaxf(fmaf(f[(size_t)iv[(size_t)u * 3 + 1] * C + c], sc, sh), 0.f);
  float a2 = fmaxf(fmaf(f[(size_t)iv[(size_t)u * 3 + 2] * C + c], sc, sh), 0.f);
  X[(size_t)u * 160 + xoff + c] = wv[(size_t)u * 3] * a0 + wv[(size_t)u * 3 + 1] * a1
                                + wv[(size_t)u * 3 + 2] * a2;
}

// ---------------- extra 1x1 conv with fused input BN ----------------
__global__ __launch_bounds__(256) void conv1x1_k(const float* __restrict__ f,
                                                 const float* __restrict__ scsh,
                                                 const float* __restrict__ we, int n,
                                                 float* __restrict__ out) {
  __shared__ float rows[256];
  int t = threadIdx.x;
  int p = blockIdx.x * 4 + (t >> 6), c = t & 63;
  rows[t] = (p < n) ? fmaxf(fmaf(f[(size_t)p * 64 + c], scsh[c], scsh[64 + c]), 0.f) : 0.f;
  __syncthreads();
  if (p >= n) return;
  const float* fr = rows + (t >> 6) * 64;
  float a = 0.f;
#pragma unroll 16
  for (int ci = 0; ci < 64; ci++) a = fmaf(fr[ci], we[ci * 64 + c], a);
  out[(size_t)p * 64 + c] = a;
}

// ---------------- dense scatter with fused BN+ReLU ----------------
__global__ void scatter_k(const float* __restrict__ pre, const float* __restrict__ scsh,
                          const int* __restrict__ c3, int n3, float* __restrict__ out0) {
  int t = blockIdx.x * 256 + threadIdx.x;
  if (t >= n3 * 64) return;
  int p = t >> 6, c = t & 63;
  const int* cc = c3 + (size_t)p * 4;
  size_t o = ((((size_t)cc[0] * 64 + c) * 6 + cc[1]) * 100 + cc[2]) * 100 + cc[3];
  out0[o] = fmaxf(fmaf(pre[t], scsh[c], scsh[64 + c]), 0.f);
}

// ---------------- head ----------------
__global__ __launch_bounds__(256) void head_k(const float* __restrict__ X,
                                              const float* __restrict__ fcw,
                                              const float* __restrict__ clsw,
                                              const float* __restrict__ regw,
                                              int n0, float* __restrict__ outc,
                                              float* __restrict__ outr) {
  __shared__ float fl[64 * 161];
  int t = threadIdx.x;
  for (int i = t; i < 64 * 160; i += 256) {
    int r = i / 160, c = i % 160;
    fl[r * 161 + c] = fcw[i];
  }
  __syncthreads();
  int wave = t >> 6, lane = t & 63;
  int u = blockIdx.x * 4 + wave;
  if (u >= n0) return;
  const float* xr = X + (size_t)u * 160;
  const float* wr = fl + (size_t)lane * 161;
  float a = 0.f;
#pragma unroll 8
  for (int i = 0; i < 160; i++) a = fmaf(xr[i], wr[i], a);
  float c = a * clsw[lane];
  float r0 = a * regw[lane], r1 = a * regw[64 + lane], r2 = a * regw[128 + lane];
  for (int off = 32; off; off >>= 1) {
    c  += __shfl_down(c, off);
    r0 += __shfl_down(r0, off);
    r1 += __shfl_down(r1, off);
    r2 += __shfl_down(r2, off);
  }
  if (lane == 0) {
    outc[u] = c;
    outr[(size_t)u * 3] = r0; outr[(size_t)u * 3 + 1] = r1; outr[(size_t)u * 3 + 2] = r2;
  }
}

// ---------------- host ----------------
extern "C" void kernel_launch(void* const* d_in, const int* in_sizes, int n_in,
                              void* d_out, int out_size, void* d_ws, size_t ws_size,
                              hipStream_t stream) {
  const float* vf  = (const float*)d_in[0];
  const int* c0 = (const int*)d_in[1];
  const int* c1 = (const int*)d_in[2];
  const int* c2 = (const int*)d_in[3];
  const int* c3 = (const int*)d_in[4];
  const float* w00 = (const float*)d_in[5];  const float* b00 = (const float*)d_in[6];
  const float* w01 = (const float*)d_in[7];  const float* b01 = (const float*)d_in[8];
  const float* wd0 = (const float*)d_in[9];  const float* bd0 = (const float*)d_in[10];
  const float* w10 = (const float*)d_in[11]; const float* b10 = (const float*)d_in[12];
  const float* w11 = (const float*)d_in[13]; const float* b11 = (const float*)d_in[14];
  const float* wd1 = (const float*)d_in[15]; const float* bd1 = (const float*)d_in[16];
  const float* w20 = (const float*)d_in[17]; const float* b20 = (const float*)d_in[18];
  const float* w21 = (const float*)d_in[19]; const float* b21 = (const float*)d_in[20];
  const float* w22 = (const float*)d_in[21]; const float* b22 = (const float*)d_in[22];
  const float* wd2 = (const float*)d_in[23]; const float* bd2 = (const float*)d_in[24];
  const float* w30 = (const float*)d_in[25]; const float* b30 = (const float*)d_in[26];
  const float* w31 = (const float*)d_in[27]; const float* b31 = (const float*)d_in[28];
  const float* w32 = (const float*)d_in[29]; const float* b32 = (const float*)d_in[30];
  const float* we  = (const float*)d_in[31]; const float* be  = (const float*)d_in[32];
  const float* fcw = (const float*)d_in[33];
  const float* clsw = (const float*)d_in[34];
  const float* regw = (const float*)d_in[35];

  int N0 = in_sizes[1] / 4, N1 = in_sizes[2] / 4, N2 = in_sizes[3] / 4, N3 = in_sizes[4] / 4;
  int maxN = N0; if (N1 > maxN) maxN = N1; if (N2 > maxN) maxN = N2; if (N3 > maxN) maxN = N3;

  auto cdiv = [](int a, int b) { return (a + b - 1) / b; };
  char* p = (char*)d_ws;
  auto alloc = [&](size_t bytes) { char* r = p; p += (bytes + 255) & ~(size_t)255; return r; };

  int* keys0 = (int*)alloc((size_t)N0 * 4);
  int* keys1 = (int*)alloc((size_t)N1 * 4);
  int* keys2 = (int*)alloc((size_t)N2 * 4);
  int* keys3 = (int*)alloc((size_t)N3 * 4);
  int* nbr0  = (int*)alloc((size_t)N0 * 27 * 4);
  int* nbrs1 = (int*)alloc((size_t)N1 * 27 * 4);
  int* nbr1  = (int*)alloc((size_t)N1 * 27 * 4);
  int* nbrs2 = (int*)alloc((size_t)N2 * 27 * 4);
  int* nbr2  = (int*)alloc((size_t)N2 * 27 * 4);
  int* nbrs3 = (int*)alloc((size_t)N3 * 27 * 4);
  int* nbr3  = (int*)alloc((size_t)N3 * 27 * 4);
  float* FA = (float*)alloc((size_t)maxN * 64 * 4);
  float* FB = (float*)alloc((size_t)maxN * 64 * 4);
  float* FC = (float*)alloc((size_t)maxN * 64 * 4);
  unsigned* FAh = (unsigned*)alloc((size_t)maxN * 32 * 4);
  unsigned* FBh = (unsigned*)alloc((size_t)maxN * 32 * 4);
  float* stats = (float*)alloc((size_t)NCH * 64 * 2 * 4);
  float* SC = (float*)alloc((size_t)15 * 128 * 4);
  int* ctrs = (int*)alloc(16 * 4);
  float* wv = (float*)alloc((size_t)N0 * 3 * 4);
  int*   iv = (int*)alloc((size_t)N0 * 3 * 4);
  float* X  = (float*)alloc((size_t)N0 * 160 * 4);
  float* pmb = (float*)alloc((size_t)N0 * 4 * 4);
  float4* kp1 = (float4*)alloc((size_t)N1 * 16);
  float4* kp2 = (float4*)alloc((size_t)N2 * 16);
  float4* kp3 = (float4*)alloc((size_t)N3 * 16);
  int* bsA = (int*)alloc(32);
  unsigned* whbuf = (unsigned*)alloc((size_t)452736 * 4);

  float* out0 = (float*)d_out;
  float* out1 = out0 + 7680000;
  float* outc = out1 + (size_t)N0 * 4;
  float* outr = outc + N0;
  float* partial = out0;  // conv partial scratch until final memset

  auto scsh = [&](int L) { return SC + (size_t)L * 128; };

  const float* wsrc[13] = {w01, wd0, w10, w11, wd1, w20, w21, w22, wd2, w30, w31, w32, nullptr};
  int wcin[13]  = {16, 16, 32, 32, 32, 64, 64, 64, 64, 64, 64, 64, 0};
  int wcout[13] = {16, 32, 32, 32, 64, 64, 64, 64, 64, 64, 64, 64, 0};
  unsigned* wdst[13];
  size_t woff = 0;
  WP13 wp{};
  int nw = 12;
  for (int i = 0; i < nw; i++) {
    wdst[i] = whbuf + woff;
    wp.l[i] = WPrep{wsrc[i], wdst[i], wcin[i], wcout[i]};
    woff += (size_t)27 * (wcin[i] / 2) * wcout[i];
  }
  for (int i = nw; i < 13; i++) wp.l[i] = WPrep{w01, wdst[0], 16, 16};

  hipMemsetAsync(ctrs, 0, 16 * 4, stream);
  wprep_k<<<dim3(216, nw), 256, 0, stream>>>(wp);
  keys_k<<<cdiv(N0, 256), 256, 0, stream>>>(c0, N0, 41, 800, 800, keys0);
  keys_k<<<cdiv(N1, 256), 256, 0, stream>>>(c1, N1, 21, 400, 400, keys1);
  keys_k<<<cdiv(N2, 256), 256, 0, stream>>>(c2, N2, 11, 200, 200, keys2);
  keys_k<<<cdiv(N3, 256), 256, 0, stream>>>(c3, N3, 6, 100, 100, keys3);
  nbr_k<<<cdiv(N0 * 27, 256), 256, 0, stream>>>(c0, N0, keys0, N0, 41, 800, 800, 1, nbr0);
  nbr_k<<<cdiv(N1 * 27, 256), 256, 0, stream>>>(c1, N1, keys0, N0, 41, 800, 800, 2, nbrs1);
  nbr_k<<<cdiv(N1 * 27, 256), 256, 0, stream>>>(c1, N1, keys1, N1, 21, 400, 400, 1, nbr1);
  nbr_k<<<cdiv(N2 * 27, 256), 256, 0, stream>>>(c2, N2, keys1, N1, 21, 400, 400, 2, nbrs2);
  nbr_k<<<cdiv(N2 * 27, 256), 256, 0, stream>>>(c2, N2, keys2, N2, 11, 200, 200, 1, nbr2);
  nbr_k<<<cdiv(N3 * 27, 256), 256, 0, stream>>>(c3, N3, keys2, N2, 11, 200, 200, 2, nbrs3);
  nbr_k<<<cdiv(N3 * 27, 256), 256, 0, stream>>>(c3, N3, keys3, N3, 6, 100, 100, 1, nbr3);
  pm_k<<<cdiv(N0, 256), 256, 0, stream>>>(vf, c0, N0, pmb, out1);
  knnprep_k<<<cdiv(N1, 256), 256, 0, stream>>>(c1, N1, 0.2f, 0.2f, 0.4f, kp1, bsA + 0);
  knnprep_k<<<cdiv(N2, 256), 256, 0, stream>>>(c2, N2, 0.4f, 0.4f, 0.8f, kp2, bsA + 1);
  knnprep_k<<<cdiv(N3, 256), 256, 0, stream>>>(c3, N3, 0.8f, 0.8f, 1.6f, kp3, bsA + 2);

  auto convh = [&](const unsigned* fhin, const int* nb, int wi, int n, int cin, int cout,
                   const float* ss) {
    dim3 g(cdiv(n, 32), NG);
    int gs = n * cout;
    const unsigned* wh = wdst[wi];
    if (cin == 16 && cout == 16)
      convh_k<16, 16><<<g, 128, 0, stream>>>(fhin, nb, wh, n, partial, gs, ss);
    else if (cin == 16 && cout == 32)
      convh_k<16, 32><<<g, 128, 0, stream>>>(fhin, nb, wh, n, partial, gs, ss);
    else if (cin == 32 && cout == 32)
      convh_k<32, 32><<<g, 128, 0, stream>>>(fhin, nb, wh, n, partial, gs, ss);
    else if (cin == 32 && cout == 64)
      convh_k<32, 64><<<g, 128, 0, stream>>>(fhin, nb, wh, n, partial, gs, ss);
    else
      convh_k<64, 64><<<g, 128, 0, stream>>>(fhin, nb, wh, n, partial, gs, ss);
  };
  auto bnp = [&](const float* bnpar, int n, int C, float* pre, unsigned* preh, int L) {
    bn_k<<<NCH, 256, 0, stream>>>(partial, NG, n * C, n, C, pre, preh, stats, bnpar,
                                  scsh(L), ctrs + L);
  };
  auto knn = [&](const float4* kp4, const int* bsl, int nl, const float* f, int C, int L,
                 int xoff) {
    knn_k<<<cdiv(N0, 4), 256, 0, stream>>>((const float4*)pmb, N0, kp4, nl, bsl, wv, iv);
    interp_k<<<cdiv(N0 * C, 256), 256, 0, stream>>>(f, C, scsh(L), wv, iv, N0, X, xoff);
  };

  // layer 0: fp32 conv from raw voxel features
  convg_k<4, 16><<<dim3(cdiv(N0, 32), NG), 128, 0, stream>>>(vf, nbr0, w00, N0, partial, N0 * 16);
  bnp(b00, N0, 16, nullptr, FAh, 0);
  convh(FAh, nbr0, 0, N0, 16, 16, scsh(0));   bnp(b01, N0, 16, nullptr, FBh, 1);
  convh(FBh, nbrs1, 1, N1, 16, 32, scsh(1));  bnp(bd0, N1, 32, nullptr, FAh, 2);
  convh(FAh, nbr1, 2, N1, 32, 32, scsh(2));   bnp(b10, N1, 32, nullptr, FBh, 3);
  convh(FBh, nbr1, 3, N1, 32, 32, scsh(3));   bnp(b11, N1, 32, FA, FAh, 4);
  knn(kp1, bsA + 0, N1, FA, 32, 4, 0);
  convh(FAh, nbrs2, 4, N2, 32, 64, scsh(4));  bnp(bd1, N2, 64, nullptr, FBh, 5);
  convh(FBh, nbr2, 5, N2, 64, 64, scsh(5));   bnp(b20, N2, 64, nullptr, FAh, 6);
  convh(FAh, nbr2, 6, N2, 64, 64, scsh(6));   bnp(b21, N2, 64, nullptr, FBh, 7);
  convh(FBh, nbr2, 7, N2, 64, 64, scsh(7));   bnp(b22, N2, 64, FA, FAh, 8);
  knn(kp2, bsA + 1, N2, FA, 64, 8, 32);
  convh(FAh, nbrs3, 8, N3, 64, 64, scsh(8));  bnp(bd2, N3, 64, nullptr, FBh, 9);
  convh(FBh, nbr3, 9, N3, 64, 64, scsh(9));   bnp(b30, N3, 64, nullptr, FAh, 10);
  convh(FAh, nbr3, 10, N3, 64, 64, scsh(10)); bnp(b31, N3, 64, nullptr, FBh, 11);
  convh(FBh, nbr3, 11, N3, 64, 64, scsh(11)); bnp(b32, N3, 64, FA, FAh, 12);
  knn(kp3, bsA + 2, N3, FA, 64, 12, 96);

  conv1x1_k<<<cdiv(N3, 4), 256, 0, stream>>>(FA, scsh(12), we, N3, FC);
  bn_k<<<NCH, 256, 0, stream>>>(FC, 1, 0, N3, 64, FB, FBh, stats, be, scsh(13), ctrs + 13);
  hipMemsetAsync(d_out, 0, (size_t)7680000 * 4, stream);
  scatter_k<<<cdiv(N3 * 64, 256), 256, 0, stream>>>(FB, scsh(13), c3, N3, out0);
  head_k<<<cdiv(N0, 4), 256, 0, stream>>>(X, fcw, clsw, regw, N0, outc, outr);
}